// Round 7
// baseline (2006.850 us; speedup 1.0000x reference)
//
#include <hip/hip_runtime.h>
#include <math.h>

#define Bn 2
#define Cn 192
#define Dn 48
#define Hn 48
#define Wn 48
#define C4 768
#define DHW (Dn*Hn*Wn)          // 110592 per batch
#define CDHW ((long)Cn*DHW)     // 21233664 per batch

typedef __attribute__((ext_vector_type(8))) short bf16x8;
typedef __attribute__((ext_vector_type(4))) float f32x4;

__device__ inline float bf2f(unsigned short u) {
    union { float f; unsigned int i; } v; v.i = ((unsigned int)u) << 16; return v.f;
}
__device__ inline unsigned short f2bf(float f) {
    union { float f; unsigned int i; } v; v.f = f;
    unsigned int r = v.i + 0x7FFFu + ((v.i >> 16) & 1u);   // RNE
    return (unsigned short)(r >> 16);
}

// ---------------- depthwise conv 7x7x7, f16 halo + fma_mix, NCDHW -> NCDHW bf16 ----
// block: 128 threads, one channel, 8(d)x16(h)x16(w) output tile.
// thread: 2(d)x8(w) outputs. Halo 14x22x22 staged as f16, row stride 28
// (56B -> conflict-free, proven round 6). Inner loop: fmaf((float)f16, f32, f32)
// -> v_fma_mix_f32 (convert folded into FMA, full fp32 rate).
#define TD 8
#define TH 16
#define TW 16
#define HD (TD+6)     // 14
#define HH (TH+6)     // 22
#define HWS 28        // padded w stride in f16 elems

__global__ __launch_bounds__(128)
void conv_dw(const float* __restrict__ x, const float* __restrict__ cw,
             const float* __restrict__ cb, unsigned short* __restrict__ yc)
{
    __shared__ _Float16 xt[HD][HH][HWS];   // 17,248 B
    __shared__ float wl[7][7][8];          //  1,568 B (kw padded to 8)
    int c = blockIdx.y;
    int s = blockIdx.x;                    // 54 tiles: 6(d) x 3(h) x 3(w)
    int wt = s % 3, ht = (s / 3) % 3, dt = s / 9;
    int d0 = dt * TD, h0 = ht * TH, w0 = wt * TW;
    int tid = threadIdx.x;

    for (int i = tid; i < 343; i += 128) {
        int kd = i / 49, r = i % 49;
        wl[kd][r / 7][r % 7] = cw[i * Cn + c];
    }

    const float* xb = x + (long)c * DHW;
    for (int u = tid; u < HD * HH * (HWS / 2); u += 128) {
        int pr = u % (HWS / 2);
        int row = u / (HWS / 2);
        int hh2 = row % HH, dd = row / HH;
        int gd = d0 - 3 + dd, gh = h0 - 3 + hh2;
        int gw0 = w0 - 3 + pr * 2;
        bool okp = (unsigned)gd < 48u && (unsigned)gh < 48u;
        const float* xr = xb + (gd * 48 + gh) * 48;
        float v0 = (okp && (unsigned)gw0 < 48u) ? xr[gw0] : 0.0f;
        float v1 = (okp && (unsigned)(gw0 + 1) < 48u) ? xr[gw0 + 1] : 0.0f;
        union { _Float16 h[2]; unsigned int u32; } pk;
        pk.h[0] = (_Float16)v0; pk.h[1] = (_Float16)v1;
        *(unsigned int*)&xt[dd][hh2][pr * 2] = pk.u32;
    }
    __syncthreads();

    int wg = tid & 1;                      // w half (8 outputs)
    int hh = (tid >> 1) & 15;              // output h within tile
    int dp = tid >> 5;                     // d pair index [0,4)
    float bias = cb[c];
    float acc[2][8];
#pragma unroll
    for (int t = 0; t < 2; ++t)
#pragma unroll
        for (int i = 0; i < 8; ++i) acc[t][i] = bias;

    for (int kh = 0; kh < 7; ++kh) {
        int hin = hh + kh;
#pragma unroll
        for (int kd = 0; kd < 7; ++kd) {
            float4 wa = *(const float4*)&wl[kd][kh][0];
            float4 wb = *(const float4*)&wl[kd][kh][4];   // .w is pad, unused
            float wv[7] = {wa.x, wa.y, wa.z, wa.w, wb.x, wb.y, wb.z};
            // t=0 uses plane dp*2+kd; t=1 uses plane dp*2+1+kd
            const _Float16* rA = &xt[dp * 2 + kd][hin][wg * 8];
            const _Float16* rB = rA + HH * HWS;           // next d plane
            _Float16 xa[14], xv[14];
            *(uint2*)&xa[0] = *(const uint2*)(rA);
            *(uint2*)&xa[4] = *(const uint2*)(rA + 4);
            *(uint2*)&xa[8] = *(const uint2*)(rA + 8);
            *(unsigned int*)&xa[12] = *(const unsigned int*)(rA + 12);
            *(uint2*)&xv[0] = *(const uint2*)(rB);
            *(uint2*)&xv[4] = *(const uint2*)(rB + 4);
            *(uint2*)&xv[8] = *(const uint2*)(rB + 8);
            *(unsigned int*)&xv[12] = *(const unsigned int*)(rB + 12);
#pragma unroll
            for (int kw = 0; kw < 7; ++kw) {
                float wk = wv[kw];
#pragma unroll
                for (int i = 0; i < 8; ++i) {
                    acc[0][i] = fmaf((float)xa[kw + i], wk, acc[0][i]);
                    acc[1][i] = fmaf((float)xv[kw + i], wk, acc[1][i]);
                }
            }
        }
    }

    unsigned short* yb = yc + (long)c * DHW;
#pragma unroll
    for (int t = 0; t < 2; ++t) {
        int dout = d0 + dp * 2 + t;
        unsigned short* op = yb + ((long)dout * 48 + h0 + hh) * 48 + w0 + wg * 8;
        union { unsigned short s2[8]; uint4 v; } o;
#pragma unroll
        for (int i = 0; i < 8; ++i) o.s2[i] = f2bf(acc[t][i]);
        *(uint4*)op = o.v;
    }
}

// ---------------- LayerNorm over C, per-batch NCDHW(bf16) -> NDHWC (bf16) ----------------
__global__ __launch_bounds__(256)
void ln_kernel(const unsigned short* __restrict__ yc, const float* __restrict__ g,
               const float* __restrict__ lb, unsigned short* __restrict__ y1)
{
    __shared__ float tile[Cn * Wn];
    __shared__ float mu_s[Wn], rs_s[Wn];
    int dh = blockIdx.x;
    long rowbase = (long)dh * Wn;
    for (int l = threadIdx.x; l < Cn * 24; l += 256) {
        int c = l / 24, wp = l % 24;
        unsigned int u = *(const unsigned int*)&yc[rowbase + (long)c * DHW + wp * 2];
        tile[c * Wn + wp * 2]     = bf2f((unsigned short)(u & 0xffffu));
        tile[c * Wn + wp * 2 + 1] = bf2f((unsigned short)(u >> 16));
    }
    __syncthreads();
    if (threadIdx.x < Wn) {
        int w = threadIdx.x;
        float s = 0.f;
        for (int c = 0; c < Cn; ++c) s += tile[c * Wn + w];
        float mu = s * (1.0f / Cn);
        float v = 0.f;
        for (int c = 0; c < Cn; ++c) { float dd = tile[c * Wn + w] - mu; v = fmaf(dd, dd, v); }
        mu_s[w] = mu;
        rs_s[w] = rsqrtf(v * (1.0f / Cn) + 1e-6f);
    }
    __syncthreads();
    long obase = (long)dh * Wn * Cn;
    for (int l = threadIdx.x; l < Cn * Wn; l += 256) {
        int w = l / Cn, c = l % Cn;
        float val = (tile[c * Wn + w] - mu_s[w]) * rs_s[w] * g[c] + lb[c];
        y1[obase + l] = f2bf(val);
    }
}

// ---------------- weight transpose+bf16: Wt[n][k] = bf16(W[k][n]) ----------------
__global__ __launch_bounds__(256)
void wtrans(const float* __restrict__ W, unsigned short* __restrict__ Wt, int K, int N)
{
    int idx = blockIdx.x * 256 + threadIdx.x;
    if (idx >= K * N) return;
    int n = idx / K, k = idx % K;
    Wt[idx] = f2bf(W[(long)k * N + n]);
}

// ---------------- W2 scale+transpose: W2s[n][k] = bf16(W2[k][n]*snx[k]) ----------------
__global__ __launch_bounds__(256)
void wscale(const float* __restrict__ W2, const float* __restrict__ snx,
            unsigned short* __restrict__ W2s)
{
    int idx = blockIdx.x * 256 + threadIdx.x;
    if (idx >= C4 * Cn) return;
    int n = idx / C4, k = idx % C4;
    W2s[idx] = f2bf(W2[(long)k * Cn + n] * snx[k]);
}

// ================= MFMA GEMM: C[M,N] = A[M,K](bf16) @ Bt[N,K](bf16)^T =========
#define BM 128
#define BN 64
#define BK 64

#define GEMM_STAGE(Aptr, Astride, Btptr, Bstride)                               \
    {                                                                           \
        _Pragma("unroll")                                                       \
        for (int i = 0; i < 4; ++i) {                                           \
            int chunk = i * 256 + tid;                                          \
            int r = chunk >> 3, cc = chunk & 7;                                 \
            bf16x8 v = *(const bf16x8*)((Aptr) + (size_t)(m0 + r) * (Astride) + k0 + cc * 8); \
            *(bf16x8*)&Asm[r * BK + ((cc ^ (r & 7)) * 8)] = v;                  \
        }                                                                       \
        _Pragma("unroll")                                                       \
        for (int i = 0; i < 2; ++i) {                                           \
            int chunk = i * 256 + tid;                                          \
            int r = chunk >> 3, cc = chunk & 7;                                 \
            bf16x8 v = *(const bf16x8*)((Btptr) + (size_t)(n0 + r) * (Bstride) + k0 + cc * 8); \
            *(bf16x8*)&Bsm[r * BK + ((cc ^ (r & 7)) * 8)] = v;                  \
        }                                                                       \
    }

#define GEMM_COMPUTE                                                            \
    _Pragma("unroll")                                                           \
    for (int kk = 0; kk < 2; ++kk) {                                            \
        bf16x8 af[4], bfr[2];                                                   \
        _Pragma("unroll")                                                       \
        for (int mi = 0; mi < 4; ++mi) {                                        \
            int r = wm * 64 + mi * 16 + lr;                                     \
            int cc = (kk * 4 + lq) ^ (r & 7);                                   \
            af[mi] = *(const bf16x8*)&Asm[r * BK + cc * 8];                     \
        }                                                                       \
        _Pragma("unroll")                                                       \
        for (int ni = 0; ni < 2; ++ni) {                                        \
            int r = wn * 32 + ni * 16 + lr;                                     \
            int cc = (kk * 4 + lq) ^ (r & 7);                                   \
            bfr[ni] = *(const bf16x8*)&Bsm[r * BK + cc * 8];                    \
        }                                                                       \
        _Pragma("unroll")                                                       \
        for (int mi = 0; mi < 4; ++mi)                                          \
            _Pragma("unroll")                                                   \
            for (int ni = 0; ni < 2; ++ni)                                      \
                acc[mi][ni] = __builtin_amdgcn_mfma_f32_16x16x32_bf16(          \
                    af[mi], bfr[ni], acc[mi][ni], 0, 0, 0);                     \
    }

// ---- GEMM up: y1 @ w1t^T + b1, GELU -> y2 bf16; fused GRN column partials ----
__global__ __launch_bounds__(256)
void gemm_up(const unsigned short* __restrict__ A, const unsigned short* __restrict__ Bt,
             const float* __restrict__ bias, unsigned short* __restrict__ Y2,
             float* __restrict__ partial)
{
    __shared__ short Asm[BM * BK];
    __shared__ short Bsm[BN * BK];
    __shared__ float colred[BN];
    int tid = threadIdx.x;
    int lane = tid & 63, wv = tid >> 6;
    int wm = wv >> 1, wn = wv & 1;
    int lr = lane & 15, lq = lane >> 4;
    long m0 = (long)blockIdx.y * BM;
    int n0 = blockIdx.x * BN;

    f32x4 acc[4][2];
#pragma unroll
    for (int mi = 0; mi < 4; ++mi)
#pragma unroll
        for (int ni = 0; ni < 2; ++ni) acc[mi][ni] = (f32x4){0.f, 0.f, 0.f, 0.f};

    for (int k0 = 0; k0 < Cn; k0 += BK) {
        GEMM_STAGE(A, Cn, Bt, Cn);
        __syncthreads();
        GEMM_COMPUTE;
        __syncthreads();
    }

    float ss[2] = {0.f, 0.f};
#pragma unroll
    for (int mi = 0; mi < 4; ++mi) {
#pragma unroll
        for (int ni = 0; ni < 2; ++ni) {
            int colg = n0 + wn * 32 + ni * 16 + lr;
            float bb = bias[colg];
            long mbase = m0 + wm * 64 + mi * 16 + lq * 4;
#pragma unroll
            for (int i = 0; i < 4; ++i) {
                float v = acc[mi][ni][i] + bb;
                v = 0.5f * v * (1.0f + erff(v * 0.70710678118654752f));
                ss[ni] = fmaf(v, v, ss[ni]);
                Y2[(mbase + i) * C4 + colg] = f2bf(v);
            }
        }
    }
    // reduce ss over the 4 lq groups (lane bits 4,5)
#pragma unroll
    for (int ni = 0; ni < 2; ++ni) {
        ss[ni] += __shfl_xor(ss[ni], 16);
        ss[ni] += __shfl_xor(ss[ni], 32);
    }
    if (wm == 0 && lq == 0) {
        colred[wn * 32 + lr]      = ss[0];
        colred[wn * 32 + 16 + lr] = ss[1];
    }
    __syncthreads();
    if (wm == 1 && lq == 0) {
        colred[wn * 32 + lr]      += ss[0];
        colred[wn * 32 + 16 + lr] += ss[1];
    }
    __syncthreads();
    if (tid < BN) partial[(size_t)blockIdx.y * C4 + n0 + tid] = colred[tid];
}

// ---- GEMM down: y2 @ w2s^T + beff + x, NDHWC -> NCDHW f32 ----
__global__ __launch_bounds__(256)
void gemm_down(const unsigned short* __restrict__ A, const unsigned short* __restrict__ Bt,
               const float* __restrict__ beff, const float* __restrict__ x,
               float* __restrict__ out)
{
    __shared__ short Asm[BM * BK];
    __shared__ short Bsm[BN * BK];
    int tid = threadIdx.x;
    int lane = tid & 63, wv = tid >> 6;
    int wm = wv >> 1, wn = wv & 1;
    int lr = lane & 15, lq = lane >> 4;
    long m0 = (long)blockIdx.y * BM;
    int n0 = blockIdx.x * BN;

    f32x4 acc[4][2];
#pragma unroll
    for (int mi = 0; mi < 4; ++mi)
#pragma unroll
        for (int ni = 0; ni < 2; ++ni) acc[mi][ni] = (f32x4){0.f, 0.f, 0.f, 0.f};

    for (int k0 = 0; k0 < C4; k0 += BK) {
        GEMM_STAGE(A, C4, Bt, C4);
        __syncthreads();
        GEMM_COMPUTE;
        __syncthreads();
    }

#pragma unroll
    for (int mi = 0; mi < 4; ++mi) {
#pragma unroll
        for (int ni = 0; ni < 2; ++ni) {
            int colg = n0 + wn * 32 + ni * 16 + lr;   // output channel c
            float be = beff[colg];
            long mbase = m0 + wm * 64 + mi * 16 + lq * 4;
            const float* xp = x + (long)colg * DHW + mbase;
            float* op = out + (long)colg * DHW + mbase;
            float4 xvv = *(const float4*)xp;
            float4 o;
            o.x = acc[mi][ni][0] + be + xvv.x;
            o.y = acc[mi][ni][1] + be + xvv.y;
            o.z = acc[mi][ni][2] + be + xvv.z;
            o.w = acc[mi][ni][3] + be + xvv.w;
            *(float4*)op = o;
        }
    }
}

// ---------------- GRN reduce: 864 partials -> gx2[n] ----------------
__global__ __launch_bounds__(256)
void grn_reduce(const float* __restrict__ partial, float* __restrict__ gx2)
{
    int n = blockIdx.x;
    const float* p = partial + n;
    float s = 0.f;
    for (int r = threadIdx.x; r < 864; r += 256) s += p[(long)r * C4];
    __shared__ float red[256];
    red[threadIdx.x] = s; __syncthreads();
    for (int st = 128; st > 0; st >>= 1) {
        if (threadIdx.x < st) red[threadIdx.x] += red[threadIdx.x + st];
        __syncthreads();
    }
    if (threadIdx.x == 0) gx2[n] = red[0];
}

// ---------------- GRN scale: snx[n] = 1 + gamma[n]*nx ----------------
__global__ __launch_bounds__(256)
void grn_snx(const float* __restrict__ gx2, const float* __restrict__ gamma,
             float* __restrict__ snx)
{
    __shared__ float red[256];
    float gx[3]; float s = 0.f;
#pragma unroll
    for (int i = 0; i < 3; ++i) {
        int n = threadIdx.x + i * 256;
        gx[i] = sqrtf(gx2[n]);
        s += gx[i];
    }
    red[threadIdx.x] = s; __syncthreads();
    for (int st = 128; st > 0; st >>= 1) {
        if (threadIdx.x < st) red[threadIdx.x] += red[threadIdx.x + st];
        __syncthreads();
    }
    float inv = 1.0f / (red[0] * (1.0f / C4) + 1e-6f);
#pragma unroll
    for (int i = 0; i < 3; ++i) {
        int n = threadIdx.x + i * 256;
        snx[n] = 1.0f + gamma[n] * gx[i] * inv;
    }
}

// ---------------- effective down-bias ----------------
__global__ __launch_bounds__(192)
void bias_eff_k(const float* __restrict__ beta, const float* __restrict__ W2,
                const float* __restrict__ b2, float* __restrict__ beff)
{
    int j = threadIdx.x;
    float s = b2[j];
    for (int k = 0; k < C4; ++k) s = fmaf(beta[k], W2[k * Cn + j], s);
    beff[j] = s;
}

extern "C" void kernel_launch(void* const* d_in, const int* in_sizes, int n_in,
                              void* d_out, int out_size, void* d_ws, size_t ws_size,
                              hipStream_t stream) {
    const float* x      = (const float*)d_in[0];
    const float* conv_w = (const float*)d_in[1];
    const float* conv_b = (const float*)d_in[2];
    const float* ln_g   = (const float*)d_in[3];
    const float* ln_b   = (const float*)d_in[4];
    const float* w1     = (const float*)d_in[5];
    const float* b1     = (const float*)d_in[6];
    const float* gg     = (const float*)d_in[7];
    const float* gb     = (const float*)d_in[8];
    const float* w2     = (const float*)d_in[9];
    const float* b2     = (const float*)d_in[10];
    float* out = (float*)d_out;
    char* ws = (char*)d_ws;

    unsigned short* y2  = (unsigned short*)(ws);                  // [M][768] bf16, overlaps yc
    unsigned short* yc  = (unsigned short*)(ws);                  // [192][DHW] bf16 (dead before y2)
    unsigned short* y1  = (unsigned short*)(ws + 169869312L);     // [M][192] bf16
    float*     partial  = (float*)(ws + 212336640L);              // [864][768] f32
    unsigned short* w1t = (unsigned short*)(ws + 214990848L);     // [768][192] bf16
    unsigned short* w2s = (unsigned short*)(ws + 215285760L);     // [192][768] bf16
    float*         gx2  = (float*)(ws + 215580672L);
    float*         snx  = (float*)(ws + 215583744L);
    float*        beff  = (float*)(ws + 215586816L);

    bias_eff_k<<<1, 192, 0, stream>>>(gb, w2, b2, beff);
    wtrans<<<(Cn * C4 + 255) / 256, 256, 0, stream>>>(w1, w1t, Cn, C4);

    for (int b = 0; b < Bn; ++b) {
        const float* xb = x + (size_t)b * CDHW;
        float* outb = out + (size_t)b * CDHW;
        dim3 gc(54, Cn);                  // 6x3x3 tiles of 8x16x16
        conv_dw<<<gc, 128, 0, stream>>>(xb, conv_w, conv_b, yc);
        ln_kernel<<<Dn * Hn, 256, 0, stream>>>(yc, ln_g, ln_b, y1);
        dim3 gu(C4 / BN, DHW / BM);
        gemm_up<<<gu, 256, 0, stream>>>(y1, w1t, b1, y2, partial);
        grn_reduce<<<C4, 256, 0, stream>>>(partial, gx2);
        grn_snx<<<1, 256, 0, stream>>>(gx2, gg, snx);
        wscale<<<(Cn * C4 + 255) / 256, 256, 0, stream>>>(w2, snx, w2s);
        dim3 gd(Cn / BN, DHW / BM);
        gemm_down<<<gd, 256, 0, stream>>>(y2, w2s, beff, xb, outb);
    }
}

// Round 8
// 1196.842 us; speedup vs baseline: 1.6768x; 1.6768x over previous
//
#include <hip/hip_runtime.h>
#include <math.h>

#define Bn 2
#define Cn 192
#define Dn 48
#define Hn 48
#define Wn 48
#define C4 768
#define DHW (Dn*Hn*Wn)          // 110592 per batch
#define CDHW ((long)Cn*DHW)     // 21233664 per batch

typedef __attribute__((ext_vector_type(8))) short bf16x8;
typedef __attribute__((ext_vector_type(4))) float f32x4;
typedef _Float16 f16x2 __attribute__((ext_vector_type(2)));

__device__ inline float bf2f(unsigned short u) {
    union { float f; unsigned int i; } v; v.i = ((unsigned int)u) << 16; return v.f;
}
__device__ inline unsigned short f2bf(float f) {
    union { float f; unsigned int i; } v; v.f = f;
    unsigned int r = v.i + 0x7FFFu + ((v.i >> 16) & 1u);   // RNE
    return (unsigned short)(r >> 16);
}
__device__ inline f16x2 u2h(unsigned int u) {
    union { unsigned int u; f16x2 h; } v; v.u = u; return v.h;
}

// ---------------- depthwise conv 7x7x7: f16 halo, XOR-swizzled 64B rows, dot2 ----
// block: 128 threads, one channel, 8(d)x16(h)x16(w) outputs.
// thread: 2(d)x8(w). Halo 14x22 rows x 32 f16 (64B, chunk^=row&3 swizzle ->
// aligned b128 reads at uniform bank load). Inner: v_dot2_f32_f16 (2 MAC/inst,
// f32 acc) + 1 fma per 7-tap row.
#define TD 8
#define TH 16
#define TW 16
#define HD (TD+6)     // 14
#define HH (TH+6)     // 22

__global__ __launch_bounds__(128)
void conv_dw(const float* __restrict__ x, const float* __restrict__ cw,
             const float* __restrict__ cb, unsigned short* __restrict__ yc)
{
    __shared__ unsigned int xt[HD * HH * 16];   // 14*22 rows x 16 u32 (32 f16) = 19,712 B
    __shared__ unsigned int wpk[7][7][3];       // f16 pairs (w0,w1)(w2,w3)(w4,w5)
    __shared__ float w6t[7][7];
    int c = blockIdx.y;
    int s = blockIdx.x;                         // 54 tiles: 6(d) x 3(h) x 3(w)
    int wt = s % 3, ht = (s / 3) % 3, dt = s / 9;
    int d0 = dt * TD, h0 = ht * TH, w0 = wt * TW;
    int tid = threadIdx.x;

    // stage packed weights
    for (int i = tid; i < 49; i += 128) {
        const float* wr = cw + (size_t)i * 7 * Cn + c;   // w[kd][kh][kw]
        float wv[7];
#pragma unroll
        for (int kw = 0; kw < 7; ++kw) wv[kw] = wr[kw * Cn];
        int kd = i / 7, kh = i % 7;
        union { f16x2 h; unsigned int u; } pk;
        pk.h = (f16x2){(_Float16)wv[0], (_Float16)wv[1]}; wpk[kd][kh][0] = pk.u;
        pk.h = (f16x2){(_Float16)wv[2], (_Float16)wv[3]}; wpk[kd][kh][1] = pk.u;
        pk.h = (f16x2){(_Float16)wv[4], (_Float16)wv[5]}; wpk[kd][kh][2] = pk.u;
        w6t[kd][kh] = wv[6];
    }

    // stage halo as f16 pairs, chunk-XOR swizzle
    const float* xb = x + (long)c * DHW;
    for (int u = tid; u < HD * HH * 16; u += 128) {
        int pr = u & 15, row = u >> 4;
        int hh2 = row % HH, dd = row / HH;
        int gd = d0 - 3 + dd, gh = h0 - 3 + hh2;
        int gw0 = w0 - 3 + pr * 2;
        bool okp = (unsigned)gd < 48u && (unsigned)gh < 48u;
        const float* xr = xb + (gd * 48 + gh) * 48;
        float v0 = (okp && (unsigned)gw0 < 48u) ? xr[gw0] : 0.0f;
        float v1 = (okp && (unsigned)(gw0 + 1) < 48u) ? xr[gw0 + 1] : 0.0f;
        union { f16x2 h; unsigned int u32; } pk;
        pk.h = (f16x2){(_Float16)v0, (_Float16)v1};
        xt[(row << 4) + ((((pr >> 2) ^ (row & 3)) << 2) | (pr & 3))] = pk.u32;
    }
    __syncthreads();

    int hh = tid & 15;                    // output h within tile (fastest -> bank spread)
    int wg = (tid >> 4) & 1;              // w half (8 outputs)
    int dp = tid >> 5;                    // d pair index [0,4)
    float bias = cb[c];
    float acc[2][8];
#pragma unroll
    for (int t = 0; t < 2; ++t)
#pragma unroll
        for (int i = 0; i < 8; ++i) acc[t][i] = bias;

    for (int kh = 0; kh < 7; ++kh) {
        unsigned int k01[7], k23[7], k45[7]; float k6[7];
#pragma unroll
        for (int kd = 0; kd < 7; ++kd) {
            k01[kd] = wpk[kd][kh][0];
            k23[kd] = wpk[kd][kh][1];
            k45[kd] = wpk[kd][kh][2];
            k6[kd]  = w6t[kd][kh];
        }
        int rbase = (dp * 2) * HH + hh + kh;
#pragma unroll
        for (int rr = 0; rr < 8; ++rr) {
            int r = rbase + rr * HH;
            const unsigned int* rowp = xt + (r << 4);
            int s3 = r & 3;
            uint4 qa = *(const uint4*)(rowp + ((wg ^ s3) << 2));
            uint4 qb = *(const uint4*)(rowp + (((wg + 1) ^ s3) << 2));
            unsigned int pp[7] = {qa.x, qa.y, qa.z, qa.w, qb.x, qb.y, qb.z};
            unsigned int ss[6];
#pragma unroll
            for (int j = 0; j < 6; ++j)
                ss[j] = __builtin_amdgcn_alignbit(pp[j + 1], pp[j], 16);
#pragma unroll
            for (int t = 0; t < 2; ++t) {
                int kd = rr - t;
                if (kd < 0 || kd > 6) continue;
                f16x2 w01 = u2h(k01[kd]), w23 = u2h(k23[kd]), w45 = u2h(k45[kd]);
                float w6 = k6[kd];
#pragma unroll
                for (int i = 0; i < 8; ++i) {
                    int j0 = i >> 1;
                    int pj = (i + 6 - (i & 1)) >> 1;
                    f16x2 a0, a1, a2;
                    if (i & 1) { a0 = u2h(ss[j0]); a1 = u2h(ss[j0 + 1]); a2 = u2h(ss[j0 + 2]); }
                    else       { a0 = u2h(pp[j0]); a1 = u2h(pp[j0 + 1]); a2 = u2h(pp[j0 + 2]); }
                    float e = (i & 1) ? (float)u2h(pp[pj]).y : (float)u2h(pp[pj]).x;
#if __has_builtin(__builtin_amdgcn_fdot2)
                    acc[t][i] = __builtin_amdgcn_fdot2(a0, w01, acc[t][i], false);
                    acc[t][i] = __builtin_amdgcn_fdot2(a1, w23, acc[t][i], false);
                    acc[t][i] = __builtin_amdgcn_fdot2(a2, w45, acc[t][i], false);
#else
                    acc[t][i] = fmaf((float)a0.x, (float)w01.x, acc[t][i]);
                    acc[t][i] = fmaf((float)a0.y, (float)w01.y, acc[t][i]);
                    acc[t][i] = fmaf((float)a1.x, (float)w23.x, acc[t][i]);
                    acc[t][i] = fmaf((float)a1.y, (float)w23.y, acc[t][i]);
                    acc[t][i] = fmaf((float)a2.x, (float)w45.x, acc[t][i]);
                    acc[t][i] = fmaf((float)a2.y, (float)w45.y, acc[t][i]);
#endif
                    acc[t][i] = fmaf(e, w6, acc[t][i]);
                }
            }
        }
    }

    unsigned short* yb = yc + (long)c * DHW;
#pragma unroll
    for (int t = 0; t < 2; ++t) {
        int dout = d0 + dp * 2 + t;
        unsigned short* op = yb + ((long)dout * 48 + h0 + hh) * 48 + w0 + wg * 8;
        union { unsigned short s2[8]; uint4 v; } o;
#pragma unroll
        for (int i = 0; i < 8; ++i) o.s2[i] = f2bf(acc[t][i]);
        *(uint4*)op = o.v;
    }
}

// ---------------- LayerNorm over C, per-batch NCDHW(bf16) -> NDHWC (bf16) ----------------
__global__ __launch_bounds__(256)
void ln_kernel(const unsigned short* __restrict__ yc, const float* __restrict__ g,
               const float* __restrict__ lb, unsigned short* __restrict__ y1)
{
    __shared__ float tile[Cn * Wn];
    __shared__ float mu_s[Wn], rs_s[Wn];
    int dh = blockIdx.x;
    long rowbase = (long)dh * Wn;
    for (int l = threadIdx.x; l < Cn * 24; l += 256) {
        int c = l / 24, wp = l % 24;
        unsigned int u = *(const unsigned int*)&yc[rowbase + (long)c * DHW + wp * 2];
        tile[c * Wn + wp * 2]     = bf2f((unsigned short)(u & 0xffffu));
        tile[c * Wn + wp * 2 + 1] = bf2f((unsigned short)(u >> 16));
    }
    __syncthreads();
    if (threadIdx.x < Wn) {
        int w = threadIdx.x;
        float s = 0.f;
        for (int c = 0; c < Cn; ++c) s += tile[c * Wn + w];
        float mu = s * (1.0f / Cn);
        float v = 0.f;
        for (int c = 0; c < Cn; ++c) { float dd = tile[c * Wn + w] - mu; v = fmaf(dd, dd, v); }
        mu_s[w] = mu;
        rs_s[w] = rsqrtf(v * (1.0f / Cn) + 1e-6f);
    }
    __syncthreads();
    long obase = (long)dh * Wn * Cn;
    for (int l = threadIdx.x; l < Cn * Wn; l += 256) {
        int w = l / Cn, c = l % Cn;
        float val = (tile[c * Wn + w] - mu_s[w]) * rs_s[w] * g[c] + lb[c];
        y1[obase + l] = f2bf(val);
    }
}

// ---------------- weight transpose+bf16: Wt[n][k] = bf16(W[k][n]) ----------------
__global__ __launch_bounds__(256)
void wtrans(const float* __restrict__ W, unsigned short* __restrict__ Wt, int K, int N)
{
    int idx = blockIdx.x * 256 + threadIdx.x;
    if (idx >= K * N) return;
    int n = idx / K, k = idx % K;
    Wt[idx] = f2bf(W[(long)k * N + n]);
}

// ---------------- W2 scale+transpose: W2s[n][k] = bf16(W2[k][n]*snx[k]) ----------------
__global__ __launch_bounds__(256)
void wscale(const float* __restrict__ W2, const float* __restrict__ snx,
            unsigned short* __restrict__ W2s)
{
    int idx = blockIdx.x * 256 + threadIdx.x;
    if (idx >= C4 * Cn) return;
    int n = idx / C4, k = idx % C4;
    W2s[idx] = f2bf(W2[(long)k * Cn + n] * snx[k]);
}

// ================= MFMA GEMM: C[M,N] = A[M,K](bf16) @ Bt[N,K](bf16)^T =========
#define BM 128
#define BN 64
#define BK 64

#define GEMM_STAGE(Aptr, Astride, Btptr, Bstride)                               \
    {                                                                           \
        _Pragma("unroll")                                                       \
        for (int i = 0; i < 4; ++i) {                                           \
            int chunk = i * 256 + tid;                                          \
            int r = chunk >> 3, cc = chunk & 7;                                 \
            bf16x8 v = *(const bf16x8*)((Aptr) + (size_t)(m0 + r) * (Astride) + k0 + cc * 8); \
            *(bf16x8*)&Asm[r * BK + ((cc ^ (r & 7)) * 8)] = v;                  \
        }                                                                       \
        _Pragma("unroll")                                                       \
        for (int i = 0; i < 2; ++i) {                                           \
            int chunk = i * 256 + tid;                                          \
            int r = chunk >> 3, cc = chunk & 7;                                 \
            bf16x8 v = *(const bf16x8*)((Btptr) + (size_t)(n0 + r) * (Bstride) + k0 + cc * 8); \
            *(bf16x8*)&Bsm[r * BK + ((cc ^ (r & 7)) * 8)] = v;                  \
        }                                                                       \
    }

#define GEMM_COMPUTE                                                            \
    _Pragma("unroll")                                                           \
    for (int kk = 0; kk < 2; ++kk) {                                            \
        bf16x8 af[4], bfr[2];                                                   \
        _Pragma("unroll")                                                       \
        for (int mi = 0; mi < 4; ++mi) {                                        \
            int r = wm * 64 + mi * 16 + lr;                                     \
            int cc = (kk * 4 + lq) ^ (r & 7);                                   \
            af[mi] = *(const bf16x8*)&Asm[r * BK + cc * 8];                     \
        }                                                                       \
        _Pragma("unroll")                                                       \
        for (int ni = 0; ni < 2; ++ni) {                                        \
            int r = wn * 32 + ni * 16 + lr;                                     \
            int cc = (kk * 4 + lq) ^ (r & 7);                                   \
            bfr[ni] = *(const bf16x8*)&Bsm[r * BK + cc * 8];                    \
        }                                                                       \
        _Pragma("unroll")                                                       \
        for (int mi = 0; mi < 4; ++mi)                                          \
            _Pragma("unroll")                                                   \
            for (int ni = 0; ni < 2; ++ni)                                      \
                acc[mi][ni] = __builtin_amdgcn_mfma_f32_16x16x32_bf16(          \
                    af[mi], bfr[ni], acc[mi][ni], 0, 0, 0);                     \
    }

// ---- GEMM up: y1 @ w1t^T + b1, GELU -> y2 bf16; fused GRN column partials ----
__global__ __launch_bounds__(256)
void gemm_up(const unsigned short* __restrict__ A, const unsigned short* __restrict__ Bt,
             const float* __restrict__ bias, unsigned short* __restrict__ Y2,
             float* __restrict__ partial)
{
    __shared__ short Asm[BM * BK];
    __shared__ short Bsm[BN * BK];
    __shared__ float colred[BN];
    int tid = threadIdx.x;
    int lane = tid & 63, wv = tid >> 6;
    int wm = wv >> 1, wn = wv & 1;
    int lr = lane & 15, lq = lane >> 4;
    long m0 = (long)blockIdx.y * BM;
    int n0 = blockIdx.x * BN;

    f32x4 acc[4][2];
#pragma unroll
    for (int mi = 0; mi < 4; ++mi)
#pragma unroll
        for (int ni = 0; ni < 2; ++ni) acc[mi][ni] = (f32x4){0.f, 0.f, 0.f, 0.f};

    for (int k0 = 0; k0 < Cn; k0 += BK) {
        GEMM_STAGE(A, Cn, Bt, Cn);
        __syncthreads();
        GEMM_COMPUTE;
        __syncthreads();
    }

    float ss[2] = {0.f, 0.f};
#pragma unroll
    for (int mi = 0; mi < 4; ++mi) {
#pragma unroll
        for (int ni = 0; ni < 2; ++ni) {
            int colg = n0 + wn * 32 + ni * 16 + lr;
            float bb = bias[colg];
            long mbase = m0 + wm * 64 + mi * 16 + lq * 4;
#pragma unroll
            for (int i = 0; i < 4; ++i) {
                float v = acc[mi][ni][i] + bb;
                v = 0.5f * v * (1.0f + erff(v * 0.70710678118654752f));
                ss[ni] = fmaf(v, v, ss[ni]);
                Y2[(mbase + i) * C4 + colg] = f2bf(v);
            }
        }
    }
#pragma unroll
    for (int ni = 0; ni < 2; ++ni) {
        ss[ni] += __shfl_xor(ss[ni], 16);
        ss[ni] += __shfl_xor(ss[ni], 32);
    }
    if (wm == 0 && lq == 0) {
        colred[wn * 32 + lr]      = ss[0];
        colred[wn * 32 + 16 + lr] = ss[1];
    }
    __syncthreads();
    if (wm == 1 && lq == 0) {
        colred[wn * 32 + lr]      += ss[0];
        colred[wn * 32 + 16 + lr] += ss[1];
    }
    __syncthreads();
    if (tid < BN) partial[(size_t)blockIdx.y * C4 + n0 + tid] = colred[tid];
}

// ---- GEMM down: y2 @ w2s^T + beff + x, NDHWC -> NCDHW f32 ----
__global__ __launch_bounds__(256)
void gemm_down(const unsigned short* __restrict__ A, const unsigned short* __restrict__ Bt,
               const float* __restrict__ beff, const float* __restrict__ x,
               float* __restrict__ out)
{
    __shared__ short Asm[BM * BK];
    __shared__ short Bsm[BN * BK];
    int tid = threadIdx.x;
    int lane = tid & 63, wv = tid >> 6;
    int wm = wv >> 1, wn = wv & 1;
    int lr = lane & 15, lq = lane >> 4;
    long m0 = (long)blockIdx.y * BM;
    int n0 = blockIdx.x * BN;

    f32x4 acc[4][2];
#pragma unroll
    for (int mi = 0; mi < 4; ++mi)
#pragma unroll
        for (int ni = 0; ni < 2; ++ni) acc[mi][ni] = (f32x4){0.f, 0.f, 0.f, 0.f};

    for (int k0 = 0; k0 < C4; k0 += BK) {
        GEMM_STAGE(A, C4, Bt, C4);
        __syncthreads();
        GEMM_COMPUTE;
        __syncthreads();
    }

#pragma unroll
    for (int mi = 0; mi < 4; ++mi) {
#pragma unroll
        for (int ni = 0; ni < 2; ++ni) {
            int colg = n0 + wn * 32 + ni * 16 + lr;
            float be = beff[colg];
            long mbase = m0 + wm * 64 + mi * 16 + lq * 4;
            const float* xp = x + (long)colg * DHW + mbase;
            float* op = out + (long)colg * DHW + mbase;
            float4 xvv = *(const float4*)xp;
            float4 o;
            o.x = acc[mi][ni][0] + be + xvv.x;
            o.y = acc[mi][ni][1] + be + xvv.y;
            o.z = acc[mi][ni][2] + be + xvv.z;
            o.w = acc[mi][ni][3] + be + xvv.w;
            *(float4*)op = o;
        }
    }
}

// ---------------- GRN reduce: 864 partials -> gx2[n] ----------------
__global__ __launch_bounds__(256)
void grn_reduce(const float* __restrict__ partial, float* __restrict__ gx2)
{
    int n = blockIdx.x;
    const float* p = partial + n;
    float s = 0.f;
    for (int r = threadIdx.x; r < 864; r += 256) s += p[(long)r * C4];
    __shared__ float red[256];
    red[threadIdx.x] = s; __syncthreads();
    for (int st = 128; st > 0; st >>= 1) {
        if (threadIdx.x < st) red[threadIdx.x] += red[threadIdx.x + st];
        __syncthreads();
    }
    if (threadIdx.x == 0) gx2[n] = red[0];
}

// ---------------- GRN scale: snx[n] = 1 + gamma[n]*nx ----------------
__global__ __launch_bounds__(256)
void grn_snx(const float* __restrict__ gx2, const float* __restrict__ gamma,
             float* __restrict__ snx)
{
    __shared__ float red[256];
    float gx[3]; float s = 0.f;
#pragma unroll
    for (int i = 0; i < 3; ++i) {
        int n = threadIdx.x + i * 256;
        gx[i] = sqrtf(gx2[n]);
        s += gx[i];
    }
    red[threadIdx.x] = s; __syncthreads();
    for (int st = 128; st > 0; st >>= 1) {
        if (threadIdx.x < st) red[threadIdx.x] += red[threadIdx.x + st];
        __syncthreads();
    }
    float inv = 1.0f / (red[0] * (1.0f / C4) + 1e-6f);
#pragma unroll
    for (int i = 0; i < 3; ++i) {
        int n = threadIdx.x + i * 256;
        snx[n] = 1.0f + gamma[n] * gx[i] * inv;
    }
}

// ---------------- effective down-bias ----------------
__global__ __launch_bounds__(192)
void bias_eff_k(const float* __restrict__ beta, const float* __restrict__ W2,
                const float* __restrict__ b2, float* __restrict__ beff)
{
    int j = threadIdx.x;
    float s = b2[j];
    for (int k = 0; k < C4; ++k) s = fmaf(beta[k], W2[k * Cn + j], s);
    beff[j] = s;
}

extern "C" void kernel_launch(void* const* d_in, const int* in_sizes, int n_in,
                              void* d_out, int out_size, void* d_ws, size_t ws_size,
                              hipStream_t stream) {
    const float* x      = (const float*)d_in[0];
    const float* conv_w = (const float*)d_in[1];
    const float* conv_b = (const float*)d_in[2];
    const float* ln_g   = (const float*)d_in[3];
    const float* ln_b   = (const float*)d_in[4];
    const float* w1     = (const float*)d_in[5];
    const float* b1     = (const float*)d_in[6];
    const float* gg     = (const float*)d_in[7];
    const float* gb     = (const float*)d_in[8];
    const float* w2     = (const float*)d_in[9];
    const float* b2     = (const float*)d_in[10];
    float* out = (float*)d_out;
    char* ws = (char*)d_ws;

    unsigned short* y2  = (unsigned short*)(ws);                  // [M][768] bf16, overlaps yc
    unsigned short* yc  = (unsigned short*)(ws);                  // [192][DHW] bf16 (dead before y2)
    unsigned short* y1  = (unsigned short*)(ws + 169869312L);     // [M][192] bf16
    float*     partial  = (float*)(ws + 212336640L);              // [864][768] f32
    unsigned short* w1t = (unsigned short*)(ws + 214990848L);     // [768][192] bf16
    unsigned short* w2s = (unsigned short*)(ws + 215285760L);     // [192][768] bf16
    float*         gx2  = (float*)(ws + 215580672L);
    float*         snx  = (float*)(ws + 215583744L);
    float*        beff  = (float*)(ws + 215586816L);

    bias_eff_k<<<1, 192, 0, stream>>>(gb, w2, b2, beff);
    wtrans<<<(Cn * C4 + 255) / 256, 256, 0, stream>>>(w1, w1t, Cn, C4);

    for (int b = 0; b < Bn; ++b) {
        const float* xb = x + (size_t)b * CDHW;
        float* outb = out + (size_t)b * CDHW;
        dim3 gc(54, Cn);                  // 6x3x3 tiles of 8x16x16
        conv_dw<<<gc, 128, 0, stream>>>(xb, conv_w, conv_b, yc);
        ln_kernel<<<Dn * Hn, 256, 0, stream>>>(yc, ln_g, ln_b, y1);
        dim3 gu(C4 / BN, DHW / BM);
        gemm_up<<<gu, 256, 0, stream>>>(y1, w1t, b1, y2, partial);
        grn_reduce<<<C4, 256, 0, stream>>>(partial, gx2);
        grn_snx<<<1, 256, 0, stream>>>(gx2, gg, snx);
        wscale<<<(Cn * C4 + 255) / 256, 256, 0, stream>>>(w2, snx, w2s);
        dim3 gd(Cn / BN, DHW / BM);
        gemm_down<<<gd, 256, 0, stream>>>(y2, w2s, beff, xb, outb);
    }
}

// Round 9
// 1093.516 us; speedup vs baseline: 1.8352x; 1.0945x over previous
//
#include <hip/hip_runtime.h>
#include <math.h>

#define Bn 2
#define Cn 192
#define Dn 48
#define Hn 48
#define Wn 48
#define C4 768
#define DHW (Dn*Hn*Wn)          // 110592 per batch
#define CDHW ((long)Cn*DHW)     // 21233664 per batch

typedef __attribute__((ext_vector_type(8))) short bf16x8;
typedef __attribute__((ext_vector_type(4))) float f32x4;

__device__ inline float bf2f(unsigned short u) {
    union { float f; unsigned int i; } v; v.i = ((unsigned int)u) << 16; return v.f;
}
__device__ inline unsigned short f2bf(float f) {
    union { float f; unsigned int i; } v; v.f = f;
    unsigned int r = v.i + 0x7FFFu + ((v.i >> 16) & 1u);   // RNE
    return (unsigned short)(r >> 16);
}
__device__ inline float blo(unsigned int u) {
    union { unsigned int i; float f; } v; v.i = u << 16; return v.f;
}
__device__ inline float bhi(unsigned int u) {
    union { unsigned int i; float f; } v; v.i = u & 0xffff0000u; return v.f;
}
__device__ inline unsigned int cvtpk_bf16(float lo, float hi) {
    unsigned int r;
    asm("v_cvt_pk_bf16_f32 %0, %1, %2" : "=v"(r) : "v"(lo), "v"(hi));
    return r;
}

// ---------------- depthwise conv 7x7x7: bf16 halo, swizzled 64B rows, scalar FMA ----
// block: 128 threads, one channel, 8(d)x16(h)x16(w) outputs; thread: 2d x 8w.
// Halo 14x22 rows x 32 bf16 (64B); 16B chunk index ^= row&3 -> wave's 64x16B
// reads spread 8-deep over 8 slots = conflict-free floor (proven round 8).
// Compute: scalar v_fma_f32 (full rate; dot2 is quarter-rate, round-8 lesson).
#define TD 8
#define TH 16
#define TW 16
#define HD (TD+6)     // 14
#define HH (TH+6)     // 22

__global__ __launch_bounds__(128, 3)
void conv_dw(const float* __restrict__ x, const float* __restrict__ cw,
             const float* __restrict__ cb, unsigned short* __restrict__ yc)
{
    __shared__ unsigned int xt[HD * HH * 16];   // 19,712 B
    __shared__ float wl[7][7][8];               //  1,568 B
    int c = blockIdx.y;
    int s = blockIdx.x;                         // 54 tiles: 6(d) x 3(h) x 3(w)
    int wt = s % 3, ht = (s / 3) % 3, dt = s / 9;
    int d0 = dt * TD, h0 = ht * TH, w0 = wt * TW;
    int tid = threadIdx.x;

    for (int i = tid; i < 343; i += 128) {
        int kd = i / 49, r = i % 49;
        wl[kd][r / 7][r % 7] = cw[i * Cn + c];
    }

    const float* xb = x + (long)c * DHW;
    for (int u = tid; u < HD * HH * 16; u += 128) {
        int pr = u & 15, row = u >> 4;
        int hh2 = row % HH, dd = row / HH;
        int gd = d0 - 3 + dd, gh = h0 - 3 + hh2;
        int gw0 = w0 - 3 + pr * 2;
        bool okp = (unsigned)gd < 48u && (unsigned)gh < 48u;
        const float* xr = xb + (gd * 48 + gh) * 48;
        float v0 = (okp && (unsigned)gw0 < 48u) ? xr[gw0] : 0.0f;
        float v1 = (okp && (unsigned)(gw0 + 1) < 48u) ? xr[gw0 + 1] : 0.0f;
        xt[(row << 4) + ((((pr >> 2) ^ (row & 3)) << 2) | (pr & 3))] = cvtpk_bf16(v0, v1);
    }
    __syncthreads();

    int hh = tid & 15;                    // output h (fastest -> bank spread)
    int wg = (tid >> 4) & 1;              // w half (8 outputs)
    int dp = tid >> 5;                    // d pair [0,4)
    float bias = cb[c];
    float acc[2][8];
#pragma unroll
    for (int t = 0; t < 2; ++t)
#pragma unroll
        for (int i = 0; i < 8; ++i) acc[t][i] = bias;

    for (int kh = 0; kh < 7; ++kh) {
        float wv[7][7];
#pragma unroll
        for (int kd = 0; kd < 7; ++kd) {
            float4 a = *(const float4*)&wl[kd][kh][0];
            float4 b = *(const float4*)&wl[kd][kh][4];
            wv[kd][0] = a.x; wv[kd][1] = a.y; wv[kd][2] = a.z; wv[kd][3] = a.w;
            wv[kd][4] = b.x; wv[kd][5] = b.y; wv[kd][6] = b.z;
        }
        int rbase = (dp * 2) * HH + hh + kh;
#pragma unroll
        for (int rr = 0; rr < 8; ++rr) {
            int r = rbase + rr * HH;
            int s3 = r & 3;
            const unsigned int* rowp = xt + (r << 4);
            uint4 qa = *(const uint4*)(rowp + ((wg ^ s3) << 2));
            uint4 qb = *(const uint4*)(rowp + (((wg + 1) ^ s3) << 2));
            unsigned int pp[7] = {qa.x, qa.y, qa.z, qa.w, qb.x, qb.y, qb.z};
            float xr[14];
#pragma unroll
            for (int j = 0; j < 7; ++j) {
                xr[2 * j]     = blo(pp[j]);
                xr[2 * j + 1] = bhi(pp[j]);
            }
#pragma unroll
            for (int t = 0; t < 2; ++t) {
                int kd = rr - t;
                if (kd < 0 || kd > 6) continue;
#pragma unroll
                for (int kw = 0; kw < 7; ++kw) {
                    float wk = wv[kd][kw];
#pragma unroll
                    for (int i = 0; i < 8; ++i)
                        acc[t][i] = fmaf(xr[kw + i], wk, acc[t][i]);
                }
            }
        }
    }

    unsigned short* yb = yc + (long)c * DHW;
#pragma unroll
    for (int t = 0; t < 2; ++t) {
        int dout = d0 + dp * 2 + t;
        unsigned short* op = yb + ((long)dout * 48 + h0 + hh) * 48 + w0 + wg * 8;
        uint4 o;
        o.x = cvtpk_bf16(acc[t][0], acc[t][1]);
        o.y = cvtpk_bf16(acc[t][2], acc[t][3]);
        o.z = cvtpk_bf16(acc[t][4], acc[t][5]);
        o.w = cvtpk_bf16(acc[t][6], acc[t][7]);
        *(uint4*)op = o;
    }
}

// ---------------- LayerNorm over C, per-batch NCDHW(bf16) -> NDHWC (bf16) ----------------
// stats by 192 threads (4 per w, c-interleaved -> 2-way LDS aliasing = free),
// single pass sum/sumsq.
__global__ __launch_bounds__(256)
void ln_kernel(const unsigned short* __restrict__ yc, const float* __restrict__ g,
               const float* __restrict__ lb, unsigned short* __restrict__ y1)
{
    __shared__ float tile[Cn * Wn];
    __shared__ float qs1[4][48], qs2[4][48];
    __shared__ float mu_s[Wn], rs_s[Wn];
    int dh = blockIdx.x;
    long rowbase = (long)dh * Wn;
    for (int l = threadIdx.x; l < Cn * 24; l += 256) {
        int c = l / 24, wp = l % 24;
        unsigned int u = *(const unsigned int*)&yc[rowbase + (long)c * DHW + wp * 2];
        tile[c * Wn + wp * 2]     = blo(u);
        tile[c * Wn + wp * 2 + 1] = bhi(u);
    }
    __syncthreads();
    if (threadIdx.x < 192) {
        int w = threadIdx.x >> 2, q = threadIdx.x & 3;
        float s1 = 0.f, s2 = 0.f;
        for (int cc = 0; cc < 48; ++cc) {
            float v = tile[(cc * 4 + q) * Wn + w];
            s1 += v; s2 = fmaf(v, v, s2);
        }
        qs1[q][w] = s1; qs2[q][w] = s2;
    }
    __syncthreads();
    if (threadIdx.x < 48) {
        int w = threadIdx.x;
        float s1 = qs1[0][w] + qs1[1][w] + qs1[2][w] + qs1[3][w];
        float s2 = qs2[0][w] + qs2[1][w] + qs2[2][w] + qs2[3][w];
        float mu = s1 * (1.0f / Cn);
        float var = s2 * (1.0f / Cn) - mu * mu;
        mu_s[w] = mu;
        rs_s[w] = rsqrtf(var + 1e-6f);
    }
    __syncthreads();
    long obase = (long)dh * Wn * Cn;
    for (int l = threadIdx.x; l < Cn * Wn; l += 256) {
        int w = l / Cn, c = l % Cn;
        float val = (tile[c * Wn + w] - mu_s[w]) * rs_s[w] * g[c] + lb[c];
        y1[obase + l] = f2bf(val);
    }
}

// ---------------- weight transpose+bf16: Wt[n][k] = bf16(W[k][n]) ----------------
__global__ __launch_bounds__(256)
void wtrans(const float* __restrict__ W, unsigned short* __restrict__ Wt, int K, int N)
{
    int idx = blockIdx.x * 256 + threadIdx.x;
    if (idx >= K * N) return;
    int n = idx / K, k = idx % K;
    Wt[idx] = f2bf(W[(long)k * N + n]);
}

// ---- W2 scale+transpose with fused GRN snx: W2s[n][k] = bf16(W2[k][n]*snx[k]) ----
__global__ __launch_bounds__(256)
void wscale(const float* __restrict__ W2, const float* __restrict__ gx2,
            const float* __restrict__ gamma, unsigned short* __restrict__ W2s)
{
    __shared__ float red[256];
    int t = threadIdx.x;
    float s = 0.f;
#pragma unroll
    for (int i = 0; i < 3; ++i) s += sqrtf(gx2[t + i * 256]);
    red[t] = s; __syncthreads();
    for (int st = 128; st > 0; st >>= 1) {
        if (t < st) red[t] += red[t + st];
        __syncthreads();
    }
    float inv = 1.0f / (red[0] * (1.0f / C4) + 1e-6f);
    int idx = blockIdx.x * 256 + t;          // [n][k], k fastest
    int n = idx / C4, k = idx % C4;
    float snx = 1.0f + gamma[k] * sqrtf(gx2[k]) * inv;
    W2s[idx] = f2bf(W2[(long)k * Cn + n] * snx);
}

// ================= MFMA GEMM: C[M,N] = A[M,K](bf16) @ Bt[N,K](bf16)^T =========
#define BM 128
#define BN 64
#define BK 64

#define GEMM_STAGE(Aptr, Astride, Btptr, Bstride)                               \
    {                                                                           \
        _Pragma("unroll")                                                       \
        for (int i = 0; i < 4; ++i) {                                           \
            int chunk = i * 256 + tid;                                          \
            int r = chunk >> 3, cc = chunk & 7;                                 \
            bf16x8 v = *(const bf16x8*)((Aptr) + (size_t)(m0 + r) * (Astride) + k0 + cc * 8); \
            *(bf16x8*)&Asm[r * BK + ((cc ^ (r & 7)) * 8)] = v;                  \
        }                                                                       \
        _Pragma("unroll")                                                       \
        for (int i = 0; i < 2; ++i) {                                           \
            int chunk = i * 256 + tid;                                          \
            int r = chunk >> 3, cc = chunk & 7;                                 \
            bf16x8 v = *(const bf16x8*)((Btptr) + (size_t)(n0 + r) * (Bstride) + k0 + cc * 8); \
            *(bf16x8*)&Bsm[r * BK + ((cc ^ (r & 7)) * 8)] = v;                  \
        }                                                                       \
    }

#define GEMM_COMPUTE                                                            \
    _Pragma("unroll")                                                           \
    for (int kk = 0; kk < 2; ++kk) {                                            \
        bf16x8 af[4], bfr[2];                                                   \
        _Pragma("unroll")                                                       \
        for (int mi = 0; mi < 4; ++mi) {                                        \
            int r = wm * 64 + mi * 16 + lr;                                     \
            int cc = (kk * 4 + lq) ^ (r & 7);                                   \
            af[mi] = *(const bf16x8*)&Asm[r * BK + cc * 8];                     \
        }                                                                       \
        _Pragma("unroll")                                                       \
        for (int ni = 0; ni < 2; ++ni) {                                        \
            int r = wn * 32 + ni * 16 + lr;                                     \
            int cc = (kk * 4 + lq) ^ (r & 7);                                   \
            bfr[ni] = *(const bf16x8*)&Bsm[r * BK + cc * 8];                    \
        }                                                                       \
        _Pragma("unroll")                                                       \
        for (int mi = 0; mi < 4; ++mi)                                          \
            _Pragma("unroll")                                                   \
            for (int ni = 0; ni < 2; ++ni)                                      \
                acc[mi][ni] = __builtin_amdgcn_mfma_f32_16x16x32_bf16(          \
                    af[mi], bfr[ni], acc[mi][ni], 0, 0, 0);                     \
    }

// ---- GEMM up: y1 @ w1t^T + b1, GELU -> y2 bf16; fused GRN column partials ----
__global__ __launch_bounds__(256)
void gemm_up(const unsigned short* __restrict__ A, const unsigned short* __restrict__ Bt,
             const float* __restrict__ bias, unsigned short* __restrict__ Y2,
             float* __restrict__ partial)
{
    __shared__ short Asm[BM * BK];
    __shared__ short Bsm[BN * BK];
    __shared__ float colred[BN];
    int tid = threadIdx.x;
    int lane = tid & 63, wv = tid >> 6;
    int wm = wv >> 1, wn = wv & 1;
    int lr = lane & 15, lq = lane >> 4;
    long m0 = (long)blockIdx.y * BM;
    int n0 = blockIdx.x * BN;

    f32x4 acc[4][2];
#pragma unroll
    for (int mi = 0; mi < 4; ++mi)
#pragma unroll
        for (int ni = 0; ni < 2; ++ni) acc[mi][ni] = (f32x4){0.f, 0.f, 0.f, 0.f};

    for (int k0 = 0; k0 < Cn; k0 += BK) {
        GEMM_STAGE(A, Cn, Bt, Cn);
        __syncthreads();
        GEMM_COMPUTE;
        __syncthreads();
    }

    float ss[2] = {0.f, 0.f};
#pragma unroll
    for (int mi = 0; mi < 4; ++mi) {
#pragma unroll
        for (int ni = 0; ni < 2; ++ni) {
            int colg = n0 + wn * 32 + ni * 16 + lr;
            float bb = bias[colg];
            long mbase = m0 + wm * 64 + mi * 16 + lq * 4;
#pragma unroll
            for (int i = 0; i < 4; ++i) {
                float v = acc[mi][ni][i] + bb;
                v = 0.5f * v * (1.0f + erff(v * 0.70710678118654752f));
                ss[ni] = fmaf(v, v, ss[ni]);
                Y2[(mbase + i) * C4 + colg] = f2bf(v);
            }
        }
    }
#pragma unroll
    for (int ni = 0; ni < 2; ++ni) {
        ss[ni] += __shfl_xor(ss[ni], 16);
        ss[ni] += __shfl_xor(ss[ni], 32);
    }
    if (wm == 0 && lq == 0) {
        colred[wn * 32 + lr]      = ss[0];
        colred[wn * 32 + 16 + lr] = ss[1];
    }
    __syncthreads();
    if (wm == 1 && lq == 0) {
        colred[wn * 32 + lr]      += ss[0];
        colred[wn * 32 + 16 + lr] += ss[1];
    }
    __syncthreads();
    if (tid < BN) partial[(size_t)blockIdx.y * C4 + n0 + tid] = colred[tid];
}

// ---- GEMM down: y2 @ w2s^T + beff + x, NDHWC -> NCDHW f32 ----
__global__ __launch_bounds__(256)
void gemm_down(const unsigned short* __restrict__ A, const unsigned short* __restrict__ Bt,
               const float* __restrict__ beff, const float* __restrict__ x,
               float* __restrict__ out)
{
    __shared__ short Asm[BM * BK];
    __shared__ short Bsm[BN * BK];
    int tid = threadIdx.x;
    int lane = tid & 63, wv = tid >> 6;
    int wm = wv >> 1, wn = wv & 1;
    int lr = lane & 15, lq = lane >> 4;
    long m0 = (long)blockIdx.y * BM;
    int n0 = blockIdx.x * BN;

    f32x4 acc[4][2];
#pragma unroll
    for (int mi = 0; mi < 4; ++mi)
#pragma unroll
        for (int ni = 0; ni < 2; ++ni) acc[mi][ni] = (f32x4){0.f, 0.f, 0.f, 0.f};

    for (int k0 = 0; k0 < C4; k0 += BK) {
        GEMM_STAGE(A, C4, Bt, C4);
        __syncthreads();
        GEMM_COMPUTE;
        __syncthreads();
    }

#pragma unroll
    for (int mi = 0; mi < 4; ++mi) {
#pragma unroll
        for (int ni = 0; ni < 2; ++ni) {
            int colg = n0 + wn * 32 + ni * 16 + lr;
            float be = beff[colg];
            long mbase = m0 + wm * 64 + mi * 16 + lq * 4;
            const float* xp = x + (long)colg * DHW + mbase;
            float* op = out + (long)colg * DHW + mbase;
            float4 xvv = *(const float4*)xp;
            float4 o;
            o.x = acc[mi][ni][0] + be + xvv.x;
            o.y = acc[mi][ni][1] + be + xvv.y;
            o.z = acc[mi][ni][2] + be + xvv.z;
            o.w = acc[mi][ni][3] + be + xvv.w;
            *(float4*)op = o;
        }
    }
}

// ---------------- GRN reduce: 864 partials -> gx2[n] ----------------
__global__ __launch_bounds__(256)
void grn_reduce(const float* __restrict__ partial, float* __restrict__ gx2)
{
    int n = blockIdx.x;
    const float* p = partial + n;
    float s = 0.f;
    for (int r = threadIdx.x; r < 864; r += 256) s += p[(long)r * C4];
    __shared__ float red[256];
    red[threadIdx.x] = s; __syncthreads();
    for (int st = 128; st > 0; st >>= 1) {
        if (threadIdx.x < st) red[threadIdx.x] += red[threadIdx.x + st];
        __syncthreads();
    }
    if (threadIdx.x == 0) gx2[n] = red[0];
}

// ---------------- effective down-bias: beff[j] = b2[j] + sum_k beta[k] W2[k][j] ----
__global__ __launch_bounds__(256)
void bias_eff_k(const float* __restrict__ beta, const float* __restrict__ W2,
                const float* __restrict__ b2, float* __restrict__ beff)
{
    __shared__ float red[256];
    int j = blockIdx.x, t = threadIdx.x;
    float s = 0.f;
#pragma unroll
    for (int i = 0; i < 3; ++i) {
        int k = t + i * 256;
        s = fmaf(beta[k], W2[(long)k * Cn + j], s);
    }
    red[t] = s; __syncthreads();
    for (int st = 128; st > 0; st >>= 1) {
        if (t < st) red[t] += red[t + st];
        __syncthreads();
    }
    if (t == 0) beff[j] = red[0] + b2[j];
}

extern "C" void kernel_launch(void* const* d_in, const int* in_sizes, int n_in,
                              void* d_out, int out_size, void* d_ws, size_t ws_size,
                              hipStream_t stream) {
    const float* x      = (const float*)d_in[0];
    const float* conv_w = (const float*)d_in[1];
    const float* conv_b = (const float*)d_in[2];
    const float* ln_g   = (const float*)d_in[3];
    const float* ln_b   = (const float*)d_in[4];
    const float* w1     = (const float*)d_in[5];
    const float* b1     = (const float*)d_in[6];
    const float* gg     = (const float*)d_in[7];
    const float* gb     = (const float*)d_in[8];
    const float* w2     = (const float*)d_in[9];
    const float* b2     = (const float*)d_in[10];
    float* out = (float*)d_out;
    char* ws = (char*)d_ws;

    unsigned short* y2  = (unsigned short*)(ws);                  // [M][768] bf16, overlaps yc
    unsigned short* yc  = (unsigned short*)(ws);                  // [192][DHW] bf16 (dead before y2)
    unsigned short* y1  = (unsigned short*)(ws + 169869312L);     // [M][192] bf16
    float*     partial  = (float*)(ws + 212336640L);              // [864][768] f32
    unsigned short* w1t = (unsigned short*)(ws + 214990848L);     // [768][192] bf16
    unsigned short* w2s = (unsigned short*)(ws + 215285760L);     // [192][768] bf16
    float*         gx2  = (float*)(ws + 215580672L);
    float*        beff  = (float*)(ws + 215586816L);

    bias_eff_k<<<Cn, 256, 0, stream>>>(gb, w2, b2, beff);
    wtrans<<<(Cn * C4 + 255) / 256, 256, 0, stream>>>(w1, w1t, Cn, C4);

    for (int b = 0; b < Bn; ++b) {
        const float* xb = x + (size_t)b * CDHW;
        float* outb = out + (size_t)b * CDHW;
        dim3 gc(54, Cn);                  // 6x3x3 tiles of 8x16x16
        conv_dw<<<gc, 128, 0, stream>>>(xb, conv_w, conv_b, yc);
        ln_kernel<<<Dn * Hn, 256, 0, stream>>>(yc, ln_g, ln_b, y1);
        dim3 gu(C4 / BN, DHW / BM);
        gemm_up<<<gu, 256, 0, stream>>>(y1, w1t, b1, y2, partial);
        grn_reduce<<<C4, 256, 0, stream>>>(partial, gx2);
        wscale<<<(Cn * C4) / 256, 256, 0, stream>>>(w2, gx2, gg, w2s);
        dim3 gd(Cn / BN, DHW / BM);
        gemm_down<<<gd, 256, 0, stream>>>(y2, w2s, beff, xb, outb);
    }
}

// Round 10
// 1051.201 us; speedup vs baseline: 1.9091x; 1.0403x over previous
//
#include <hip/hip_runtime.h>
#include <math.h>

#define Bn 2
#define Cn 192
#define Dn 48
#define Hn 48
#define Wn 48
#define C4 768
#define DHW (Dn*Hn*Wn)          // 110592 per batch
#define CDHW ((long)Cn*DHW)     // 21233664 per batch

typedef __attribute__((ext_vector_type(8))) short bf16x8;
typedef __attribute__((ext_vector_type(4))) float f32x4;

__device__ inline float bf2f(unsigned short u) {
    union { float f; unsigned int i; } v; v.i = ((unsigned int)u) << 16; return v.f;
}
__device__ inline unsigned short f2bf(float f) {
    union { float f; unsigned int i; } v; v.f = f;
    unsigned int r = v.i + 0x7FFFu + ((v.i >> 16) & 1u);   // RNE
    return (unsigned short)(r >> 16);
}
__device__ inline float blo(unsigned int u) {
    union { unsigned int i; float f; } v; v.i = u << 16; return v.f;
}
__device__ inline float bhi(unsigned int u) {
    union { unsigned int i; float f; } v; v.i = u & 0xffff0000u; return v.f;
}
__device__ inline unsigned int cvtpk_bf16(float lo, float hi) {
    unsigned int r;
    asm("v_cvt_pk_bf16_f32 %0, %1, %2" : "=v"(r) : "v"(lo), "v"(hi));
    return r;
}
__device__ inline unsigned int pk_f16(float a, float b) {   // (f16(a) lo, f16(b) hi)
    unsigned int r;
    asm("v_cvt_pkrtz_f16_f32 %0, %1, %2" : "=v"(r) : "v"(a), "v"(b));
    return r;
}
__device__ inline unsigned int pkfma_h(unsigned int x, unsigned int w, unsigned int c) {
    unsigned int r;
    asm("v_pk_fma_f16 %0, %1, %2, %3" : "=v"(r) : "v"(x), "v"(w), "v"(c));
    return r;
}

// ---------------- depthwise conv 7x7x7: f16-pair halo, swizzled 64B rows, pk_fma_f16 ----
// block: 128 threads, one channel, 8(d)x16(h)x16(w) outputs; thread: 2d x 8w.
// Halo 14x22 rows x 16 u32 (f16 pairs, 64B); chunk ^= row&3 swizzle (reads at
// the 8-phase optimum, proven r8/r9). Weights as (w,w) f16x2, b32 broadcast
// (uniform b128 reads book phantom conflicts - r9 lesson). Inner loop:
// v_pk_fma_f16 = 2 FMA/issue at full rate; odd taps use alignbit-shifted pairs.
#define TD 8
#define TH 16
#define TW 16
#define HD (TD+6)     // 14
#define HH (TH+6)     // 22

__global__ __launch_bounds__(128)
void conv_dw(const float* __restrict__ x, const float* __restrict__ cw,
             const float* __restrict__ cb, unsigned short* __restrict__ yc)
{
    __shared__ unsigned int xt[HD * HH * 16];   // 19,712 B
    __shared__ unsigned int wpair[7][7][7];     //  1,372 B  (w,w) f16 pairs
    int c = blockIdx.y;
    int s = blockIdx.x;                         // 54 tiles: 6(d) x 3(h) x 3(w)
    int wt = s % 3, ht = (s / 3) % 3, dt = s / 9;
    int d0 = dt * TD, h0 = ht * TH, w0 = wt * TW;
    int tid = threadIdx.x;

    for (int i = tid; i < 343; i += 128) {
        int kd = i / 49, r = i % 49;
        float w = cw[i * Cn + c];
        wpair[kd][r / 7][r % 7] = pk_f16(w, w);
    }

    const float* xb = x + (long)c * DHW;
    for (int u = tid; u < HD * HH * 16; u += 128) {
        int pr = u & 15, row = u >> 4;
        int hh2 = row % HH, dd = row / HH;
        int gd = d0 - 3 + dd, gh = h0 - 3 + hh2;
        int gw0 = w0 - 3 + pr * 2;
        bool okp = (unsigned)gd < 48u && (unsigned)gh < 48u;
        const float* xr = xb + (gd * 48 + gh) * 48;
        float v0 = (okp && (unsigned)gw0 < 48u) ? xr[gw0] : 0.0f;
        float v1 = (okp && (unsigned)(gw0 + 1) < 48u) ? xr[gw0 + 1] : 0.0f;
        xt[(row << 4) + ((((pr >> 2) ^ (row & 3)) << 2) | (pr & 3))] = pk_f16(v0, v1);
    }
    __syncthreads();

    int hh = tid & 15;                    // output h (fastest -> bank spread)
    int wg = (tid >> 4) & 1;              // w half (8 outputs)
    int dp = tid >> 5;                    // d pair [0,4)
    float bias = cb[c];
    unsigned int bias2 = pk_f16(bias, bias);
    unsigned int acc[2][4];               // acc[t][m] = outputs (2m, 2m+1) of d-out t
#pragma unroll
    for (int t = 0; t < 2; ++t)
#pragma unroll
        for (int m = 0; m < 4; ++m) acc[t][m] = bias2;

    for (int kh = 0; kh < 7; ++kh) {
        unsigned int wp[7][7];
#pragma unroll
        for (int kd = 0; kd < 7; ++kd)
#pragma unroll
            for (int kw = 0; kw < 7; ++kw)
                wp[kd][kw] = wpair[kd][kh][kw];           // b32 broadcast (free)
        int rbase = (dp * 2) * HH + hh + kh;
#pragma unroll
        for (int rr = 0; rr < 8; ++rr) {
            int r = rbase + rr * HH;
            int s3 = r & 3;
            const unsigned int* rowp = xt + (r << 4);
            uint4 qa = *(const uint4*)(rowp + ((wg ^ s3) << 2));
            uint4 qb = *(const uint4*)(rowp + (((wg + 1) ^ s3) << 2));
            unsigned int pp[7] = {qa.x, qa.y, qa.z, qa.w, qb.x, qb.y, qb.z};
            unsigned int ss[6];
#pragma unroll
            for (int j = 0; j < 6; ++j)
                ss[j] = __builtin_amdgcn_alignbit(pp[j + 1], pp[j], 16);
#pragma unroll
            for (int t = 0; t < 2; ++t) {
                int kd = rr - t;
                if (kd < 0 || kd > 6) continue;
#pragma unroll
                for (int m = 0; m < 4; ++m) {
                    unsigned int a = acc[t][m];
                    a = pkfma_h(pp[m],     wp[kd][0], a);
                    a = pkfma_h(ss[m],     wp[kd][1], a);
                    a = pkfma_h(pp[m + 1], wp[kd][2], a);
                    a = pkfma_h(ss[m + 1], wp[kd][3], a);
                    a = pkfma_h(pp[m + 2], wp[kd][4], a);
                    a = pkfma_h(ss[m + 2], wp[kd][5], a);
                    a = pkfma_h(pp[m + 3], wp[kd][6], a);
                    acc[t][m] = a;
                }
            }
        }
    }

    unsigned short* yb = yc + (long)c * DHW;
#pragma unroll
    for (int t = 0; t < 2; ++t) {
        int dout = d0 + dp * 2 + t;
        unsigned short* op = yb + ((long)dout * 48 + h0 + hh) * 48 + w0 + wg * 8;
        uint4 o;
#pragma unroll
        for (int m = 0; m < 4; ++m) {
            union { unsigned int u; _Float16 h[2]; } cv; cv.u = acc[t][m];
            ((unsigned int*)&o)[m] = cvtpk_bf16((float)cv.h[0], (float)cv.h[1]);
        }
        *(uint4*)op = o;
    }
}

// ---------------- LayerNorm over C, per-batch NCDHW(bf16) -> NDHWC (bf16) ----------------
__global__ __launch_bounds__(256)
void ln_kernel(const unsigned short* __restrict__ yc, const float* __restrict__ g,
               const float* __restrict__ lb, unsigned short* __restrict__ y1)
{
    __shared__ float tile[Cn * Wn];
    __shared__ float qs1[4][48], qs2[4][48];
    __shared__ float mu_s[Wn], rs_s[Wn];
    int dh = blockIdx.x;
    long rowbase = (long)dh * Wn;
    for (int l = threadIdx.x; l < Cn * 24; l += 256) {
        int c = l / 24, wp = l % 24;
        unsigned int u = *(const unsigned int*)&yc[rowbase + (long)c * DHW + wp * 2];
        tile[c * Wn + wp * 2]     = blo(u);
        tile[c * Wn + wp * 2 + 1] = bhi(u);
    }
    __syncthreads();
    if (threadIdx.x < 192) {
        int w = threadIdx.x >> 2, q = threadIdx.x & 3;
        float s1 = 0.f, s2 = 0.f;
        for (int cc = 0; cc < 48; ++cc) {
            float v = tile[(cc * 4 + q) * Wn + w];
            s1 += v; s2 = fmaf(v, v, s2);
        }
        qs1[q][w] = s1; qs2[q][w] = s2;
    }
    __syncthreads();
    if (threadIdx.x < 48) {
        int w = threadIdx.x;
        float s1 = qs1[0][w] + qs1[1][w] + qs1[2][w] + qs1[3][w];
        float s2 = qs2[0][w] + qs2[1][w] + qs2[2][w] + qs2[3][w];
        float mu = s1 * (1.0f / Cn);
        float var = s2 * (1.0f / Cn) - mu * mu;
        mu_s[w] = mu;
        rs_s[w] = rsqrtf(var + 1e-6f);
    }
    __syncthreads();
    long obase = (long)dh * Wn * Cn;
    for (int l = threadIdx.x; l < Cn * Wn; l += 256) {
        int w = l / Cn, c = l % Cn;
        float val = (tile[c * Wn + w] - mu_s[w]) * rs_s[w] * g[c] + lb[c];
        y1[obase + l] = f2bf(val);
    }
}

// ---------------- weight transpose+bf16: Wt[n][k] = bf16(W[k][n]) ----------------
__global__ __launch_bounds__(256)
void wtrans(const float* __restrict__ W, unsigned short* __restrict__ Wt, int K, int N)
{
    int idx = blockIdx.x * 256 + threadIdx.x;
    if (idx >= K * N) return;
    int n = idx / K, k = idx % K;
    Wt[idx] = f2bf(W[(long)k * N + n]);
}

// ---- W2 scale+transpose with fused GRN snx: W2s[n][k] = bf16(W2[k][n]*snx[k]) ----
__global__ __launch_bounds__(256)
void wscale(const float* __restrict__ W2, const float* __restrict__ gx2,
            const float* __restrict__ gamma, unsigned short* __restrict__ W2s)
{
    __shared__ float red[256];
    int t = threadIdx.x;
    float s = 0.f;
#pragma unroll
    for (int i = 0; i < 3; ++i) s += sqrtf(gx2[t + i * 256]);
    red[t] = s; __syncthreads();
    for (int st = 128; st > 0; st >>= 1) {
        if (t < st) red[t] += red[t + st];
        __syncthreads();
    }
    float inv = 1.0f / (red[0] * (1.0f / C4) + 1e-6f);
    int idx = blockIdx.x * 256 + t;          // [n][k], k fastest
    int n = idx / C4, k = idx % C4;
    float snx = 1.0f + gamma[k] * sqrtf(gx2[k]) * inv;
    W2s[idx] = f2bf(W2[(long)k * Cn + n] * snx);
}

// ================= MFMA GEMM: C[M,N] = A[M,K](bf16) @ Bt[N,K](bf16)^T =========
#define BM 128
#define BN 64
#define BK 64

#define GEMM_STAGE(Aptr, Astride, Btptr, Bstride)                               \
    {                                                                           \
        _Pragma("unroll")                                                       \
        for (int i = 0; i < 4; ++i) {                                           \
            int chunk = i * 256 + tid;                                          \
            int r = chunk >> 3, cc = chunk & 7;                                 \
            bf16x8 v = *(const bf16x8*)((Aptr) + (size_t)(m0 + r) * (Astride) + k0 + cc * 8); \
            *(bf16x8*)&Asm[r * BK + ((cc ^ (r & 7)) * 8)] = v;                  \
        }                                                                       \
        _Pragma("unroll")                                                       \
        for (int i = 0; i < 2; ++i) {                                           \
            int chunk = i * 256 + tid;                                          \
            int r = chunk >> 3, cc = chunk & 7;                                 \
            bf16x8 v = *(const bf16x8*)((Btptr) + (size_t)(n0 + r) * (Bstride) + k0 + cc * 8); \
            *(bf16x8*)&Bsm[r * BK + ((cc ^ (r & 7)) * 8)] = v;                  \
        }                                                                       \
    }

#define GEMM_COMPUTE                                                            \
    _Pragma("unroll")                                                           \
    for (int kk = 0; kk < 2; ++kk) {                                            \
        bf16x8 af[4], bfr[2];                                                   \
        _Pragma("unroll")                                                       \
        for (int mi = 0; mi < 4; ++mi) {                                        \
            int r = wm * 64 + mi * 16 + lr;                                     \
            int cc = (kk * 4 + lq) ^ (r & 7);                                   \
            af[mi] = *(const bf16x8*)&Asm[r * BK + cc * 8];                     \
        }                                                                       \
        _Pragma("unroll")                                                       \
        for (int ni = 0; ni < 2; ++ni) {                                        \
            int r = wn * 32 + ni * 16 + lr;                                     \
            int cc = (kk * 4 + lq) ^ (r & 7);                                   \
            bfr[ni] = *(const bf16x8*)&Bsm[r * BK + cc * 8];                    \
        }                                                                       \
        _Pragma("unroll")                                                       \
        for (int mi = 0; mi < 4; ++mi)                                          \
            _Pragma("unroll")                                                   \
            for (int ni = 0; ni < 2; ++ni)                                      \
                acc[mi][ni] = __builtin_amdgcn_mfma_f32_16x16x32_bf16(          \
                    af[mi], bfr[ni], acc[mi][ni], 0, 0, 0);                     \
    }

// ---- GEMM up: y1 @ w1t^T + b1, GELU -> y2 bf16; fused GRN column partials ----
__global__ __launch_bounds__(256)
void gemm_up(const unsigned short* __restrict__ A, const unsigned short* __restrict__ Bt,
             const float* __restrict__ bias, unsigned short* __restrict__ Y2,
             float* __restrict__ partial)
{
    __shared__ short Asm[BM * BK];
    __shared__ short Bsm[BN * BK];
    __shared__ float colred[BN];
    int tid = threadIdx.x;
    int lane = tid & 63, wv = tid >> 6;
    int wm = wv >> 1, wn = wv & 1;
    int lr = lane & 15, lq = lane >> 4;
    long m0 = (long)blockIdx.y * BM;
    int n0 = blockIdx.x * BN;

    f32x4 acc[4][2];
#pragma unroll
    for (int mi = 0; mi < 4; ++mi)
#pragma unroll
        for (int ni = 0; ni < 2; ++ni) acc[mi][ni] = (f32x4){0.f, 0.f, 0.f, 0.f};

    for (int k0 = 0; k0 < Cn; k0 += BK) {
        GEMM_STAGE(A, Cn, Bt, Cn);
        __syncthreads();
        GEMM_COMPUTE;
        __syncthreads();
    }

    float ss[2] = {0.f, 0.f};
#pragma unroll
    for (int mi = 0; mi < 4; ++mi) {
#pragma unroll
        for (int ni = 0; ni < 2; ++ni) {
            int colg = n0 + wn * 32 + ni * 16 + lr;
            float bb = bias[colg];
            long mbase = m0 + wm * 64 + mi * 16 + lq * 4;
#pragma unroll
            for (int i = 0; i < 4; ++i) {
                float v = acc[mi][ni][i] + bb;
                v = 0.5f * v * (1.0f + erff(v * 0.70710678118654752f));
                ss[ni] = fmaf(v, v, ss[ni]);
                Y2[(mbase + i) * C4 + colg] = f2bf(v);
            }
        }
    }
#pragma unroll
    for (int ni = 0; ni < 2; ++ni) {
        ss[ni] += __shfl_xor(ss[ni], 16);
        ss[ni] += __shfl_xor(ss[ni], 32);
    }
    if (wm == 0 && lq == 0) {
        colred[wn * 32 + lr]      = ss[0];
        colred[wn * 32 + 16 + lr] = ss[1];
    }
    __syncthreads();
    if (wm == 1 && lq == 0) {
        colred[wn * 32 + lr]      += ss[0];
        colred[wn * 32 + 16 + lr] += ss[1];
    }
    __syncthreads();
    if (tid < BN) partial[(size_t)blockIdx.y * C4 + n0 + tid] = colred[tid];
}

// ---- GEMM down: y2 @ w2s^T + beff + x, NDHWC -> NCDHW f32 ----
__global__ __launch_bounds__(256)
void gemm_down(const unsigned short* __restrict__ A, const unsigned short* __restrict__ Bt,
               const float* __restrict__ beff, const float* __restrict__ x,
               float* __restrict__ out)
{
    __shared__ short Asm[BM * BK];
    __shared__ short Bsm[BN * BK];
    int tid = threadIdx.x;
    int lane = tid & 63, wv = tid >> 6;
    int wm = wv >> 1, wn = wv & 1;
    int lr = lane & 15, lq = lane >> 4;
    long m0 = (long)blockIdx.y * BM;
    int n0 = blockIdx.x * BN;

    f32x4 acc[4][2];
#pragma unroll
    for (int mi = 0; mi < 4; ++mi)
#pragma unroll
        for (int ni = 0; ni < 2; ++ni) acc[mi][ni] = (f32x4){0.f, 0.f, 0.f, 0.f};

    for (int k0 = 0; k0 < C4; k0 += BK) {
        GEMM_STAGE(A, C4, Bt, C4);
        __syncthreads();
        GEMM_COMPUTE;
        __syncthreads();
    }

#pragma unroll
    for (int mi = 0; mi < 4; ++mi) {
#pragma unroll
        for (int ni = 0; ni < 2; ++ni) {
            int colg = n0 + wn * 32 + ni * 16 + lr;
            float be = beff[colg];
            long mbase = m0 + wm * 64 + mi * 16 + lq * 4;
            const float* xp = x + (long)colg * DHW + mbase;
            float* op = out + (long)colg * DHW + mbase;
            float4 xvv = *(const float4*)xp;
            float4 o;
            o.x = acc[mi][ni][0] + be + xvv.x;
            o.y = acc[mi][ni][1] + be + xvv.y;
            o.z = acc[mi][ni][2] + be + xvv.z;
            o.w = acc[mi][ni][3] + be + xvv.w;
            *(float4*)op = o;
        }
    }
}

// ---------------- GRN reduce: 864 partials -> gx2[n] ----------------
__global__ __launch_bounds__(256)
void grn_reduce(const float* __restrict__ partial, float* __restrict__ gx2)
{
    int n = blockIdx.x;
    const float* p = partial + n;
    float s = 0.f;
    for (int r = threadIdx.x; r < 864; r += 256) s += p[(long)r * C4];
    __shared__ float red[256];
    red[threadIdx.x] = s; __syncthreads();
    for (int st = 128; st > 0; st >>= 1) {
        if (threadIdx.x < st) red[threadIdx.x] += red[threadIdx.x + st];
        __syncthreads();
    }
    if (threadIdx.x == 0) gx2[n] = red[0];
}

// ---------------- effective down-bias: beff[j] = b2[j] + sum_k beta[k] W2[k][j] ----
__global__ __launch_bounds__(256)
void bias_eff_k(const float* __restrict__ beta, const float* __restrict__ W2,
                const float* __restrict__ b2, float* __restrict__ beff)
{
    __shared__ float red[256];
    int j = blockIdx.x, t = threadIdx.x;
    float s = 0.f;
#pragma unroll
    for (int i = 0; i < 3; ++i) {
        int k = t + i * 256;
        s = fmaf(beta[k], W2[(long)k * Cn + j], s);
    }
    red[t] = s; __syncthreads();
    for (int st = 128; st > 0; st >>= 1) {
        if (t < st) red[t] += red[t + st];
        __syncthreads();
    }
    if (t == 0) beff[j] = red[0] + b2[j];
}

extern "C" void kernel_launch(void* const* d_in, const int* in_sizes, int n_in,
                              void* d_out, int out_size, void* d_ws, size_t ws_size,
                              hipStream_t stream) {
    const float* x      = (const float*)d_in[0];
    const float* conv_w = (const float*)d_in[1];
    const float* conv_b = (const float*)d_in[2];
    const float* ln_g   = (const float*)d_in[3];
    const float* ln_b   = (const float*)d_in[4];
    const float* w1     = (const float*)d_in[5];
    const float* b1     = (const float*)d_in[6];
    const float* gg     = (const float*)d_in[7];
    const float* gb     = (const float*)d_in[8];
    const float* w2     = (const float*)d_in[9];
    const float* b2     = (const float*)d_in[10];
    float* out = (float*)d_out;
    char* ws = (char*)d_ws;

    unsigned short* y2  = (unsigned short*)(ws);                  // [M][768] bf16, overlaps yc
    unsigned short* yc  = (unsigned short*)(ws);                  // [192][DHW] bf16 (dead before y2)
    unsigned short* y1  = (unsigned short*)(ws + 169869312L);     // [M][192] bf16
    float*     partial  = (float*)(ws + 212336640L);              // [864][768] f32
    unsigned short* w1t = (unsigned short*)(ws + 214990848L);     // [768][192] bf16
    unsigned short* w2s = (unsigned short*)(ws + 215285760L);     // [192][768] bf16
    float*         gx2  = (float*)(ws + 215580672L);
    float*        beff  = (float*)(ws + 215586816L);

    bias_eff_k<<<Cn, 256, 0, stream>>>(gb, w2, b2, beff);
    wtrans<<<(Cn * C4 + 255) / 256, 256, 0, stream>>>(w1, w1t, Cn, C4);

    for (int b = 0; b < Bn; ++b) {
        const float* xb = x + (size_t)b * CDHW;
        float* outb = out + (size_t)b * CDHW;
        dim3 gc(54, Cn);                  // 6x3x3 tiles of 8x16x16
        conv_dw<<<gc, 128, 0, stream>>>(xb, conv_w, conv_b, yc);
        ln_kernel<<<Dn * Hn, 256, 0, stream>>>(yc, ln_g, ln_b, y1);
        dim3 gu(C4 / BN, DHW / BM);
        gemm_up<<<gu, 256, 0, stream>>>(y1, w1t, b1, y2, partial);
        grn_reduce<<<C4, 256, 0, stream>>>(partial, gx2);
        wscale<<<(Cn * C4) / 256, 256, 0, stream>>>(w2, gx2, gg, w2s);
        dim3 gd(Cn / BN, DHW / BM);
        gemm_down<<<gd, 256, 0, stream>>>(y2, w2s, beff, xb, outb);
    }
}

// Round 11
// 1049.967 us; speedup vs baseline: 1.9113x; 1.0012x over previous
//
#include <hip/hip_runtime.h>
#include <math.h>

#define Bn 2
#define Cn 192
#define Dn 48
#define Hn 48
#define Wn 48
#define C4 768
#define DHW (Dn*Hn*Wn)          // 110592 per batch
#define CDHW ((long)Cn*DHW)     // 21233664 per batch

typedef __attribute__((ext_vector_type(8))) short bf16x8;
typedef __attribute__((ext_vector_type(4))) float f32x4;

__device__ inline float bf2f(unsigned short u) {
    union { float f; unsigned int i; } v; v.i = ((unsigned int)u) << 16; return v.f;
}
__device__ inline unsigned short f2bf(float f) {
    union { float f; unsigned int i; } v; v.f = f;
    unsigned int r = v.i + 0x7FFFu + ((v.i >> 16) & 1u);   // RNE
    return (unsigned short)(r >> 16);
}
__device__ inline float blo(unsigned int u) {
    union { unsigned int i; float f; } v; v.i = u << 16; return v.f;
}
__device__ inline float bhi(unsigned int u) {
    union { unsigned int i; float f; } v; v.i = u & 0xffff0000u; return v.f;
}
__device__ inline unsigned int cvtpk_bf16(float lo, float hi) {
    unsigned int r;
    asm("v_cvt_pk_bf16_f32 %0, %1, %2" : "=v"(r) : "v"(lo), "v"(hi));
    return r;
}
__device__ inline unsigned int pk_f16(float a, float b) {   // (f16(a) lo, f16(b) hi)
    unsigned int r;
    asm("v_cvt_pkrtz_f16_f32 %0, %1, %2" : "=v"(r) : "v"(a), "v"(b));
    return r;
}
__device__ inline unsigned int pkfma_h(unsigned int x, unsigned int w, unsigned int c) {
    unsigned int r;
    asm("v_pk_fma_f16 %0, %1, %2, %3" : "=v"(r) : "v"(x), "v"(w), "v"(c));
    return r;
}

// ---------------- depthwise conv 7x7x7: f16-pair halo, swizzled 64B rows, pk_fma_f16 ----
// block: 128 threads, one channel, 8(d)x16(h)x16(w) outputs; thread: 2d x 8w.
// Halo 14x22 rows x 16 u32 (f16 pairs, 64B); chunk ^= row&3 swizzle (proven r8/r9).
// Weights (w,w) f16x2, b32 broadcast. Inner: v_pk_fma_f16 = 2 FMA/issue full rate.
// __launch_bounds__(128,2): r10 fix — at 64 VGPRs the 49 live weight pairs forced
// remat/spill (~6.6K extra VALU inst/wave from counter arithmetic); occupancy is
// LDS-bound (21.5KB -> 7 blocks/CU) so a 256-VGPR budget costs nothing.
#define TD 8
#define TH 16
#define TW 16
#define HD (TD+6)     // 14
#define HH (TH+6)     // 22

__global__ __launch_bounds__(128, 2)
void conv_dw(const float* __restrict__ x, const float* __restrict__ cw,
             const float* __restrict__ cb, unsigned short* __restrict__ yc)
{
    __shared__ unsigned int xt[HD * HH * 16];   // 19,712 B
    __shared__ unsigned int wpair[7][7][7];     //  1,372 B  (w,w) f16 pairs
    int c = blockIdx.y;
    int s = blockIdx.x;                         // 54 tiles: 6(d) x 3(h) x 3(w)
    int wt = s % 3, ht = (s / 3) % 3, dt = s / 9;
    int d0 = dt * TD, h0 = ht * TH, w0 = wt * TW;
    int tid = threadIdx.x;

    for (int i = tid; i < 343; i += 128) {
        int kd = i / 49, r = i % 49;
        float w = cw[i * Cn + c];
        wpair[kd][r / 7][r % 7] = pk_f16(w, w);
    }

    const float* xb = x + (long)c * DHW;
    for (int u = tid; u < HD * HH * 16; u += 128) {
        int pr = u & 15, row = u >> 4;
        int hh2 = row % HH, dd = row / HH;
        int gd = d0 - 3 + dd, gh = h0 - 3 + hh2;
        int gw0 = w0 - 3 + pr * 2;
        bool okp = (unsigned)gd < 48u && (unsigned)gh < 48u;
        const float* xr = xb + (gd * 48 + gh) * 48;
        float v0 = (okp && (unsigned)gw0 < 48u) ? xr[gw0] : 0.0f;
        float v1 = (okp && (unsigned)(gw0 + 1) < 48u) ? xr[gw0 + 1] : 0.0f;
        xt[(row << 4) + ((((pr >> 2) ^ (row & 3)) << 2) | (pr & 3))] = pk_f16(v0, v1);
    }
    __syncthreads();

    int hh = tid & 15;                    // output h (fastest -> bank spread)
    int wg = (tid >> 4) & 1;              // w half (8 outputs)
    int dp = tid >> 5;                    // d pair [0,4)
    float bias = cb[c];
    unsigned int bias2 = pk_f16(bias, bias);
    unsigned int acc[2][4];               // acc[t][m] = outputs (2m, 2m+1) of d-out t
#pragma unroll
    for (int t = 0; t < 2; ++t)
#pragma unroll
        for (int m = 0; m < 4; ++m) acc[t][m] = bias2;

    for (int kh = 0; kh < 7; ++kh) {
        unsigned int wp[7][7];
#pragma unroll
        for (int kd = 0; kd < 7; ++kd)
#pragma unroll
            for (int kw = 0; kw < 7; ++kw)
                wp[kd][kw] = wpair[kd][kh][kw];           // b32 broadcast (free)
        int rbase = (dp * 2) * HH + hh + kh;
#pragma unroll
        for (int rr = 0; rr < 8; ++rr) {
            int r = rbase + rr * HH;
            int s3 = r & 3;
            const unsigned int* rowp = xt + (r << 4);
            uint4 qa = *(const uint4*)(rowp + ((wg ^ s3) << 2));
            uint4 qb = *(const uint4*)(rowp + (((wg + 1) ^ s3) << 2));
            unsigned int pp[7] = {qa.x, qa.y, qa.z, qa.w, qb.x, qb.y, qb.z};
            unsigned int ss[6];
#pragma unroll
            for (int j = 0; j < 6; ++j)
                ss[j] = __builtin_amdgcn_alignbit(pp[j + 1], pp[j], 16);
#pragma unroll
            for (int t = 0; t < 2; ++t) {
                int kd = rr - t;
                if (kd < 0 || kd > 6) continue;
#pragma unroll
                for (int m = 0; m < 4; ++m) {
                    unsigned int a = acc[t][m];
                    a = pkfma_h(pp[m],     wp[kd][0], a);
                    a = pkfma_h(ss[m],     wp[kd][1], a);
                    a = pkfma_h(pp[m + 1], wp[kd][2], a);
                    a = pkfma_h(ss[m + 1], wp[kd][3], a);
                    a = pkfma_h(pp[m + 2], wp[kd][4], a);
                    a = pkfma_h(ss[m + 2], wp[kd][5], a);
                    a = pkfma_h(pp[m + 3], wp[kd][6], a);
                    acc[t][m] = a;
                }
            }
        }
    }

    unsigned short* yb = yc + (long)c * DHW;
#pragma unroll
    for (int t = 0; t < 2; ++t) {
        int dout = d0 + dp * 2 + t;
        unsigned short* op = yb + ((long)dout * 48 + h0 + hh) * 48 + w0 + wg * 8;
        uint4 o;
#pragma unroll
        for (int m = 0; m < 4; ++m) {
            union { unsigned int u; _Float16 h[2]; } cv; cv.u = acc[t][m];
            ((unsigned int*)&o)[m] = cvtpk_bf16((float)cv.h[0], (float)cv.h[1]);
        }
        *(uint4*)op = o;
    }
}

// ---------------- LayerNorm over C, per-batch NCDHW(bf16) -> NDHWC (bf16) ----------------
__global__ __launch_bounds__(256)
void ln_kernel(const unsigned short* __restrict__ yc, const float* __restrict__ g,
               const float* __restrict__ lb, unsigned short* __restrict__ y1)
{
    __shared__ float tile[Cn * Wn];
    __shared__ float qs1[4][48], qs2[4][48];
    __shared__ float mu_s[Wn], rs_s[Wn];
    int dh = blockIdx.x;
    long rowbase = (long)dh * Wn;
    for (int l = threadIdx.x; l < Cn * 24; l += 256) {
        int c = l / 24, wp = l % 24;
        unsigned int u = *(const unsigned int*)&yc[rowbase + (long)c * DHW + wp * 2];
        tile[c * Wn + wp * 2]     = blo(u);
        tile[c * Wn + wp * 2 + 1] = bhi(u);
    }
    __syncthreads();
    if (threadIdx.x < 192) {
        int w = threadIdx.x >> 2, q = threadIdx.x & 3;
        float s1 = 0.f, s2 = 0.f;
        for (int cc = 0; cc < 48; ++cc) {
            float v = tile[(cc * 4 + q) * Wn + w];
            s1 += v; s2 = fmaf(v, v, s2);
        }
        qs1[q][w] = s1; qs2[q][w] = s2;
    }
    __syncthreads();
    if (threadIdx.x < 48) {
        int w = threadIdx.x;
        float s1 = qs1[0][w] + qs1[1][w] + qs1[2][w] + qs1[3][w];
        float s2 = qs2[0][w] + qs2[1][w] + qs2[2][w] + qs2[3][w];
        float mu = s1 * (1.0f / Cn);
        float var = s2 * (1.0f / Cn) - mu * mu;
        mu_s[w] = mu;
        rs_s[w] = rsqrtf(var + 1e-6f);
    }
    __syncthreads();
    long obase = (long)dh * Wn * Cn;
    for (int l = threadIdx.x; l < Cn * Wn; l += 256) {
        int w = l / Cn, c = l % Cn;
        float val = (tile[c * Wn + w] - mu_s[w]) * rs_s[w] * g[c] + lb[c];
        y1[obase + l] = f2bf(val);
    }
}

// ---------------- weight transpose+bf16: Wt[n][k] = bf16(W[k][n]) ----------------
__global__ __launch_bounds__(256)
void wtrans(const float* __restrict__ W, unsigned short* __restrict__ Wt, int K, int N)
{
    int idx = blockIdx.x * 256 + threadIdx.x;
    if (idx >= K * N) return;
    int n = idx / K, k = idx % K;
    Wt[idx] = f2bf(W[(long)k * N + n]);
}

// ---- W2 scale+transpose with fused GRN snx: W2s[n][k] = bf16(W2[k][n]*snx[k]) ----
__global__ __launch_bounds__(256)
void wscale(const float* __restrict__ W2, const float* __restrict__ gx2,
            const float* __restrict__ gamma, unsigned short* __restrict__ W2s)
{
    __shared__ float red[256];
    int t = threadIdx.x;
    float s = 0.f;
#pragma unroll
    for (int i = 0; i < 3; ++i) s += sqrtf(gx2[t + i * 256]);
    red[t] = s; __syncthreads();
    for (int st = 128; st > 0; st >>= 1) {
        if (t < st) red[t] += red[t + st];
        __syncthreads();
    }
    float inv = 1.0f / (red[0] * (1.0f / C4) + 1e-6f);
    int idx = blockIdx.x * 256 + t;          // [n][k], k fastest
    int n = idx / C4, k = idx % C4;
    float snx = 1.0f + gamma[k] * sqrtf(gx2[k]) * inv;
    W2s[idx] = f2bf(W2[(long)k * Cn + n] * snx);
}

// ================= MFMA GEMM: C[M,N] = A[M,K](bf16) @ Bt[N,K](bf16)^T =========
#define BM 128
#define BN 64
#define BK 64

#define GEMM_STAGE(Aptr, Astride, Btptr, Bstride)                               \
    {                                                                           \
        _Pragma("unroll")                                                       \
        for (int i = 0; i < 4; ++i) {                                           \
            int chunk = i * 256 + tid;                                          \
            int r = chunk >> 3, cc = chunk & 7;                                 \
            bf16x8 v = *(const bf16x8*)((Aptr) + (size_t)(m0 + r) * (Astride) + k0 + cc * 8); \
            *(bf16x8*)&Asm[r * BK + ((cc ^ (r & 7)) * 8)] = v;                  \
        }                                                                       \
        _Pragma("unroll")                                                       \
        for (int i = 0; i < 2; ++i) {                                           \
            int chunk = i * 256 + tid;                                          \
            int r = chunk >> 3, cc = chunk & 7;                                 \
            bf16x8 v = *(const bf16x8*)((Btptr) + (size_t)(n0 + r) * (Bstride) + k0 + cc * 8); \
            *(bf16x8*)&Bsm[r * BK + ((cc ^ (r & 7)) * 8)] = v;                  \
        }                                                                       \
    }

#define GEMM_COMPUTE                                                            \
    _Pragma("unroll")                                                           \
    for (int kk = 0; kk < 2; ++kk) {                                            \
        bf16x8 af[4], bfr[2];                                                   \
        _Pragma("unroll")                                                       \
        for (int mi = 0; mi < 4; ++mi) {                                        \
            int r = wm * 64 + mi * 16 + lr;                                     \
            int cc = (kk * 4 + lq) ^ (r & 7);                                   \
            af[mi] = *(const bf16x8*)&Asm[r * BK + cc * 8];                     \
        }                                                                       \
        _Pragma("unroll")                                                       \
        for (int ni = 0; ni < 2; ++ni) {                                        \
            int r = wn * 32 + ni * 16 + lr;                                     \
            int cc = (kk * 4 + lq) ^ (r & 7);                                   \
            bfr[ni] = *(const bf16x8*)&Bsm[r * BK + cc * 8];                    \
        }                                                                       \
        _Pragma("unroll")                                                       \
        for (int mi = 0; mi < 4; ++mi)                                          \
            _Pragma("unroll")                                                   \
            for (int ni = 0; ni < 2; ++ni)                                      \
                acc[mi][ni] = __builtin_amdgcn_mfma_f32_16x16x32_bf16(          \
                    af[mi], bfr[ni], acc[mi][ni], 0, 0, 0);                     \
    }

// ---- GEMM up: y1 @ w1t^T + b1, GELU -> y2 bf16; fused GRN column partials ----
__global__ __launch_bounds__(256)
void gemm_up(const unsigned short* __restrict__ A, const unsigned short* __restrict__ Bt,
             const float* __restrict__ bias, unsigned short* __restrict__ Y2,
             float* __restrict__ partial)
{
    __shared__ short Asm[BM * BK];
    __shared__ short Bsm[BN * BK];
    __shared__ float colred[BN];
    int tid = threadIdx.x;
    int lane = tid & 63, wv = tid >> 6;
    int wm = wv >> 1, wn = wv & 1;
    int lr = lane & 15, lq = lane >> 4;
    long m0 = (long)blockIdx.y * BM;
    int n0 = blockIdx.x * BN;

    f32x4 acc[4][2];
#pragma unroll
    for (int mi = 0; mi < 4; ++mi)
#pragma unroll
        for (int ni = 0; ni < 2; ++ni) acc[mi][ni] = (f32x4){0.f, 0.f, 0.f, 0.f};

    for (int k0 = 0; k0 < Cn; k0 += BK) {
        GEMM_STAGE(A, Cn, Bt, Cn);
        __syncthreads();
        GEMM_COMPUTE;
        __syncthreads();
    }

    float ss[2] = {0.f, 0.f};
#pragma unroll
    for (int mi = 0; mi < 4; ++mi) {
#pragma unroll
        for (int ni = 0; ni < 2; ++ni) {
            int colg = n0 + wn * 32 + ni * 16 + lr;
            float bb = bias[colg];
            long mbase = m0 + wm * 64 + mi * 16 + lq * 4;
#pragma unroll
            for (int i = 0; i < 4; ++i) {
                float v = acc[mi][ni][i] + bb;
                v = 0.5f * v * (1.0f + erff(v * 0.70710678118654752f));
                ss[ni] = fmaf(v, v, ss[ni]);
                Y2[(mbase + i) * C4 + colg] = f2bf(v);
            }
        }
    }
#pragma unroll
    for (int ni = 0; ni < 2; ++ni) {
        ss[ni] += __shfl_xor(ss[ni], 16);
        ss[ni] += __shfl_xor(ss[ni], 32);
    }
    if (wm == 0 && lq == 0) {
        colred[wn * 32 + lr]      = ss[0];
        colred[wn * 32 + 16 + lr] = ss[1];
    }
    __syncthreads();
    if (wm == 1 && lq == 0) {
        colred[wn * 32 + lr]      += ss[0];
        colred[wn * 32 + 16 + lr] += ss[1];
    }
    __syncthreads();
    if (tid < BN) partial[(size_t)blockIdx.y * C4 + n0 + tid] = colred[tid];
}

// ---- GEMM down: y2 @ w2s^T + beff + x, NDHWC -> NCDHW f32 ----
__global__ __launch_bounds__(256)
void gemm_down(const unsigned short* __restrict__ A, const unsigned short* __restrict__ Bt,
               const float* __restrict__ beff, const float* __restrict__ x,
               float* __restrict__ out)
{
    __shared__ short Asm[BM * BK];
    __shared__ short Bsm[BN * BK];
    int tid = threadIdx.x;
    int lane = tid & 63, wv = tid >> 6;
    int wm = wv >> 1, wn = wv & 1;
    int lr = lane & 15, lq = lane >> 4;
    long m0 = (long)blockIdx.y * BM;
    int n0 = blockIdx.x * BN;

    f32x4 acc[4][2];
#pragma unroll
    for (int mi = 0; mi < 4; ++mi)
#pragma unroll
        for (int ni = 0; ni < 2; ++ni) acc[mi][ni] = (f32x4){0.f, 0.f, 0.f, 0.f};

    for (int k0 = 0; k0 < C4; k0 += BK) {
        GEMM_STAGE(A, C4, Bt, C4);
        __syncthreads();
        GEMM_COMPUTE;
        __syncthreads();
    }

#pragma unroll
    for (int mi = 0; mi < 4; ++mi) {
#pragma unroll
        for (int ni = 0; ni < 2; ++ni) {
            int colg = n0 + wn * 32 + ni * 16 + lr;
            float be = beff[colg];
            long mbase = m0 + wm * 64 + mi * 16 + lq * 4;
            const float* xp = x + (long)colg * DHW + mbase;
            float* op = out + (long)colg * DHW + mbase;
            float4 xvv = *(const float4*)xp;
            float4 o;
            o.x = acc[mi][ni][0] + be + xvv.x;
            o.y = acc[mi][ni][1] + be + xvv.y;
            o.z = acc[mi][ni][2] + be + xvv.z;
            o.w = acc[mi][ni][3] + be + xvv.w;
            *(float4*)op = o;
        }
    }
}

// ---------------- GRN reduce: 864 partials -> gx2[n] ----------------
__global__ __launch_bounds__(256)
void grn_reduce(const float* __restrict__ partial, float* __restrict__ gx2)
{
    int n = blockIdx.x;
    const float* p = partial + n;
    float s = 0.f;
    for (int r = threadIdx.x; r < 864; r += 256) s += p[(long)r * C4];
    __shared__ float red[256];
    red[threadIdx.x] = s; __syncthreads();
    for (int st = 128; st > 0; st >>= 1) {
        if (threadIdx.x < st) red[threadIdx.x] += red[threadIdx.x + st];
        __syncthreads();
    }
    if (threadIdx.x == 0) gx2[n] = red[0];
}

// ---------------- effective down-bias: beff[j] = b2[j] + sum_k beta[k] W2[k][j] ----
__global__ __launch_bounds__(256)
void bias_eff_k(const float* __restrict__ beta, const float* __restrict__ W2,
                const float* __restrict__ b2, float* __restrict__ beff)
{
    __shared__ float red[256];
    int j = blockIdx.x, t = threadIdx.x;
    float s = 0.f;
#pragma unroll
    for (int i = 0; i < 3; ++i) {
        int k = t + i * 256;
        s = fmaf(beta[k], W2[(long)k * Cn + j], s);
    }
    red[t] = s; __syncthreads();
    for (int st = 128; st > 0; st >>= 1) {
        if (t < st) red[t] += red[t + st];
        __syncthreads();
    }
    if (t == 0) beff[j] = red[0] + b2[j];
}

extern "C" void kernel_launch(void* const* d_in, const int* in_sizes, int n_in,
                              void* d_out, int out_size, void* d_ws, size_t ws_size,
                              hipStream_t stream) {
    const float* x      = (const float*)d_in[0];
    const float* conv_w = (const float*)d_in[1];
    const float* conv_b = (const float*)d_in[2];
    const float* ln_g   = (const float*)d_in[3];
    const float* ln_b   = (const float*)d_in[4];
    const float* w1     = (const float*)d_in[5];
    const float* b1     = (const float*)d_in[6];
    const float* gg     = (const float*)d_in[7];
    const float* gb     = (const float*)d_in[8];
    const float* w2     = (const float*)d_in[9];
    const float* b2     = (const float*)d_in[10];
    float* out = (float*)d_out;
    char* ws = (char*)d_ws;

    unsigned short* y2  = (unsigned short*)(ws);                  // [M][768] bf16, overlaps yc
    unsigned short* yc  = (unsigned short*)(ws);                  // [192][DHW] bf16 (dead before y2)
    unsigned short* y1  = (unsigned short*)(ws + 169869312L);     // [M][192] bf16
    float*     partial  = (float*)(ws + 212336640L);              // [864][768] f32
    unsigned short* w1t = (unsigned short*)(ws + 214990848L);     // [768][192] bf16
    unsigned short* w2s = (unsigned short*)(ws + 215285760L);     // [192][768] bf16
    float*         gx2  = (float*)(ws + 215580672L);
    float*        beff  = (float*)(ws + 215586816L);

    bias_eff_k<<<Cn, 256, 0, stream>>>(gb, w2, b2, beff);
    wtrans<<<(Cn * C4 + 255) / 256, 256, 0, stream>>>(w1, w1t, Cn, C4);

    for (int b = 0; b < Bn; ++b) {
        const float* xb = x + (size_t)b * CDHW;
        float* outb = out + (size_t)b * CDHW;
        dim3 gc(54, Cn);                  // 6x3x3 tiles of 8x16x16
        conv_dw<<<gc, 128, 0, stream>>>(xb, conv_w, conv_b, yc);
        ln_kernel<<<Dn * Hn, 256, 0, stream>>>(yc, ln_g, ln_b, y1);
        dim3 gu(C4 / BN, DHW / BM);
        gemm_up<<<gu, 256, 0, stream>>>(y1, w1t, b1, y2, partial);
        grn_reduce<<<C4, 256, 0, stream>>>(partial, gx2);
        wscale<<<(Cn * C4) / 256, 256, 0, stream>>>(w2, gx2, gg, w2s);
        dim3 gd(Cn / BN, DHW / BM);
        gemm_down<<<gd, 256, 0, stream>>>(y2, w2s, beff, xb, outb);
    }
}

// Round 12
// 945.900 us; speedup vs baseline: 2.1216x; 1.1100x over previous
//
#include <hip/hip_runtime.h>
#include <math.h>

#define Bn 2
#define Cn 192
#define Dn 48
#define Hn 48
#define Wn 48
#define C4 768
#define DHW (Dn*Hn*Wn)          // 110592 per batch
#define CDHW ((long)Cn*DHW)     // 21233664 per batch

typedef __attribute__((ext_vector_type(8))) short bf16x8;
typedef __attribute__((ext_vector_type(4))) float f32x4;

__device__ inline float bf2f(unsigned short u) {
    union { float f; unsigned int i; } v; v.i = ((unsigned int)u) << 16; return v.f;
}
__device__ inline unsigned short f2bf(float f) {
    union { float f; unsigned int i; } v; v.f = f;
    unsigned int r = v.i + 0x7FFFu + ((v.i >> 16) & 1u);   // RNE
    return (unsigned short)(r >> 16);
}
__device__ inline float blo(unsigned int u) {
    union { unsigned int i; float f; } v; v.i = u << 16; return v.f;
}
__device__ inline float bhi(unsigned int u) {
    union { unsigned int i; float f; } v; v.i = u & 0xffff0000u; return v.f;
}
__device__ inline unsigned int cvtpk_bf16(float lo, float hi) {
    unsigned int r;
    asm("v_cvt_pk_bf16_f32 %0, %1, %2" : "=v"(r) : "v"(lo), "v"(hi));
    return r;
}

// ---- B-Toeplitz table: btp[(c*49 + kd*7+kh)*64 + lane][j] = wt[kd][kh][8g+j-n]
// (n = lane&15, g = lane>>4; zero outside the 7-tap band). Lane-indexed so the
// conv wave loads its B-fragment with one coalesced dwordx4.
__global__ __launch_bounds__(256)
void btoep_k(const float* __restrict__ cw, unsigned short* __restrict__ btp)
{
    int idx = blockIdx.x * 256 + threadIdx.x;   // (c*49 + kdkh)*64 + lane
    int lane = idx & 63;
    int t = idx >> 6;
    int kdkh = t % 49, c = t / 49;
    int n = lane & 15, g = lane >> 4;
    unsigned short v[8];
#pragma unroll
    for (int j = 0; j < 8; ++j) {
        int kw = 8 * g + j - n;
        v[j] = (kw >= 0 && kw <= 6) ? f2bf(cw[(kdkh * 7 + kw) * Cn + c])
                                    : (unsigned short)0;
    }
    *(uint4*)(btp + (size_t)idx * 8) = *(uint4*)v;
}

// ---------------- depthwise conv 7x7x7 on the MATRIX pipe (Toeplitz MFMA) ----
// r11 rationale: vector pipe is exhausted (pk_fma_f16 issues at ~1 FLOP/lane/cy,
// same as scalar f32 — r10 counter arithmetic). Per (kd,kh): one
// mfma_f32_16x16x32_bf16 computes the banded-Toeplitz w-conv of a 16h x 16w
// tile: A[m][k] = halo[d+kd][m+kh][k] (one ds_read_b128/lane), B[k][n] =
// wt[k-n] from the precomputed table. block: 128 thr = 2 waves, one channel,
// 8d x 16h x 16w outputs; wave wv owns d-slices 4wv..4wv+3; A-frag(kd,t) reuse
// via plane index kd+t -> 10 reads per kh per wave. f32 accumulation.
#define TD 8
#define TH 16
#define TW 16
#define HD (TD+6)     // 14
#define HH (TH+6)     // 22

__global__ __launch_bounds__(128)
void conv_dw(const float* __restrict__ x, const unsigned short* __restrict__ btp,
             const float* __restrict__ cb, unsigned short* __restrict__ yc)
{
    __shared__ unsigned int xt[HD * HH * 16];   // 19,712 B (bf16-pair halo rows of 64B)
    int c = blockIdx.y;
    int s = blockIdx.x;                         // 54 tiles: 6(d) x 3(h) x 3(w)
    int wt = s % 3, ht = (s / 3) % 3, dt = s / 9;
    int d0 = dt * TD, h0 = ht * TH, w0 = wt * TW;
    int tid = threadIdx.x;

    const float* xb = x + (long)c * DHW;
    for (int u = tid; u < HD * HH * 16; u += 128) {
        int pr = u & 15, row = u >> 4;
        int hh2 = row % HH, dd = row / HH;
        int gd = d0 - 3 + dd, gh = h0 - 3 + hh2;
        int gw0 = w0 - 3 + pr * 2;
        bool okp = (unsigned)gd < 48u && (unsigned)gh < 48u;
        const float* xr = xb + (gd * 48 + gh) * 48;
        float v0 = (okp && (unsigned)gw0 < 48u) ? xr[gw0] : 0.0f;
        float v1 = (okp && (unsigned)(gw0 + 1) < 48u) ? xr[gw0 + 1] : 0.0f;
        xt[(row << 4) + ((((pr >> 2) ^ (row & 3)) << 2) | (pr & 3))] = cvtpk_bf16(v0, v1);
    }
    __syncthreads();

    int lane = tid & 63, wv = tid >> 6;
    int lr = lane & 15, g = lane >> 4;
    float bias = cb[c];
    f32x4 acc[4];
#pragma unroll
    for (int t = 0; t < 4; ++t) acc[t] = (f32x4){bias, bias, bias, bias};

    const unsigned short* bchan = btp + (size_t)c * 49 * 512;   // 49*64*8
    const unsigned short* xt16 = (const unsigned short*)xt;

    for (int kh = 0; kh < 7; ++kh) {
        bf16x8 Bf[7];
#pragma unroll
        for (int kd = 0; kd < 7; ++kd)
            Bf[kd] = *(const bf16x8*)(bchan + (size_t)((kd * 7 + kh) * 64 + lane) * 8);
        bf16x8 Af[10];
#pragma unroll
        for (int p = 0; p < 10; ++p) {
            int r = (4 * wv + p) * HH + kh + lr;          // halo row for plane p, out-h lr
            Af[p] = *(const bf16x8*)(xt16 + (r << 5) + ((g ^ (r & 3)) << 3));
        }
#pragma unroll
        for (int kd = 0; kd < 7; ++kd)
#pragma unroll
            for (int t = 0; t < 4; ++t)
                acc[t] = __builtin_amdgcn_mfma_f32_16x16x32_bf16(
                    Af[kd + t], Bf[kd], acc[t], 0, 0, 0);
    }

    unsigned short* yb = yc + (long)c * DHW;
#pragma unroll
    for (int t = 0; t < 4; ++t) {
        int d = d0 + 4 * wv + t;
#pragma unroll
        for (int i = 0; i < 4; ++i) {
            int h = h0 + g * 4 + i;
            yb[((long)d * 48 + h) * 48 + w0 + lr] = f2bf(acc[t][i]);
        }
    }
}

// ---------------- LayerNorm over C, per-batch NCDHW(bf16) -> NDHWC (bf16) ----------------
__global__ __launch_bounds__(256)
void ln_kernel(const unsigned short* __restrict__ yc, const float* __restrict__ g,
               const float* __restrict__ lb, unsigned short* __restrict__ y1)
{
    __shared__ float tile[Cn * Wn];
    __shared__ float qs1[4][48], qs2[4][48];
    __shared__ float mu_s[Wn], rs_s[Wn];
    int dh = blockIdx.x;
    long rowbase = (long)dh * Wn;
    for (int l = threadIdx.x; l < Cn * 24; l += 256) {
        int c = l / 24, wp = l % 24;
        unsigned int u = *(const unsigned int*)&yc[rowbase + (long)c * DHW + wp * 2];
        tile[c * Wn + wp * 2]     = blo(u);
        tile[c * Wn + wp * 2 + 1] = bhi(u);
    }
    __syncthreads();
    if (threadIdx.x < 192) {
        int w = threadIdx.x >> 2, q = threadIdx.x & 3;
        float s1 = 0.f, s2 = 0.f;
        for (int cc = 0; cc < 48; ++cc) {
            float v = tile[(cc * 4 + q) * Wn + w];
            s1 += v; s2 = fmaf(v, v, s2);
        }
        qs1[q][w] = s1; qs2[q][w] = s2;
    }
    __syncthreads();
    if (threadIdx.x < 48) {
        int w = threadIdx.x;
        float s1 = qs1[0][w] + qs1[1][w] + qs1[2][w] + qs1[3][w];
        float s2 = qs2[0][w] + qs2[1][w] + qs2[2][w] + qs2[3][w];
        float mu = s1 * (1.0f / Cn);
        float var = s2 * (1.0f / Cn) - mu * mu;
        mu_s[w] = mu;
        rs_s[w] = rsqrtf(var + 1e-6f);
    }
    __syncthreads();
    long obase = (long)dh * Wn * Cn;
    for (int l = threadIdx.x; l < Cn * Wn; l += 256) {
        int w = l / Cn, c = l % Cn;
        float val = (tile[c * Wn + w] - mu_s[w]) * rs_s[w] * g[c] + lb[c];
        y1[obase + l] = f2bf(val);
    }
}

// ---------------- weight transpose+bf16: Wt[n][k] = bf16(W[k][n]) ----------------
__global__ __launch_bounds__(256)
void wtrans(const float* __restrict__ W, unsigned short* __restrict__ Wt, int K, int N)
{
    int idx = blockIdx.x * 256 + threadIdx.x;
    if (idx >= K * N) return;
    int n = idx / K, k = idx % K;
    Wt[idx] = f2bf(W[(long)k * N + n]);
}

// ---- W2 scale+transpose with fused GRN snx: W2s[n][k] = bf16(W2[k][n]*snx[k]) ----
__global__ __launch_bounds__(256)
void wscale(const float* __restrict__ W2, const float* __restrict__ gx2,
            const float* __restrict__ gamma, unsigned short* __restrict__ W2s)
{
    __shared__ float red[256];
    int t = threadIdx.x;
    float s = 0.f;
#pragma unroll
    for (int i = 0; i < 3; ++i) s += sqrtf(gx2[t + i * 256]);
    red[t] = s; __syncthreads();
    for (int st = 128; st > 0; st >>= 1) {
        if (t < st) red[t] += red[t + st];
        __syncthreads();
    }
    float inv = 1.0f / (red[0] * (1.0f / C4) + 1e-6f);
    int idx = blockIdx.x * 256 + t;          // [n][k], k fastest
    int n = idx / C4, k = idx % C4;
    float snx = 1.0f + gamma[k] * sqrtf(gx2[k]) * inv;
    W2s[idx] = f2bf(W2[(long)k * Cn + n] * snx);
}

// ================= MFMA GEMM: C[M,N] = A[M,K](bf16) @ Bt[N,K](bf16)^T =========
#define BM 128
#define BN 64
#define BK 64

#define GEMM_STAGE(Aptr, Astride, Btptr, Bstride)                               \
    {                                                                           \
        _Pragma("unroll")                                                       \
        for (int i = 0; i < 4; ++i) {                                           \
            int chunk = i * 256 + tid;                                          \
            int r = chunk >> 3, cc = chunk & 7;                                 \
            bf16x8 v = *(const bf16x8*)((Aptr) + (size_t)(m0 + r) * (Astride) + k0 + cc * 8); \
            *(bf16x8*)&Asm[r * BK + ((cc ^ (r & 7)) * 8)] = v;                  \
        }                                                                       \
        _Pragma("unroll")                                                       \
        for (int i = 0; i < 2; ++i) {                                           \
            int chunk = i * 256 + tid;                                          \
            int r = chunk >> 3, cc = chunk & 7;                                 \
            bf16x8 v = *(const bf16x8*)((Btptr) + (size_t)(n0 + r) * (Bstride) + k0 + cc * 8); \
            *(bf16x8*)&Bsm[r * BK + ((cc ^ (r & 7)) * 8)] = v;                  \
        }                                                                       \
    }

#define GEMM_COMPUTE                                                            \
    _Pragma("unroll")                                                           \
    for (int kk = 0; kk < 2; ++kk) {                                            \
        bf16x8 af[4], bfr[2];                                                   \
        _Pragma("unroll")                                                       \
        for (int mi = 0; mi < 4; ++mi) {                                        \
            int r = wm * 64 + mi * 16 + lr;                                     \
            int cc = (kk * 4 + lq) ^ (r & 7);                                   \
            af[mi] = *(const bf16x8*)&Asm[r * BK + cc * 8];                     \
        }                                                                       \
        _Pragma("unroll")                                                       \
        for (int ni = 0; ni < 2; ++ni) {                                        \
            int r = wn * 32 + ni * 16 + lr;                                     \
            int cc = (kk * 4 + lq) ^ (r & 7);                                   \
            bfr[ni] = *(const bf16x8*)&Bsm[r * BK + cc * 8];                    \
        }                                                                       \
        _Pragma("unroll")                                                       \
        for (int mi = 0; mi < 4; ++mi)                                          \
            _Pragma("unroll")                                                   \
            for (int ni = 0; ni < 2; ++ni)                                      \
                acc[mi][ni] = __builtin_amdgcn_mfma_f32_16x16x32_bf16(          \
                    af[mi], bfr[ni], acc[mi][ni], 0, 0, 0);                     \
    }

// ---- GEMM up: y1 @ w1t^T + b1, GELU -> y2 bf16; fused GRN column partials ----
__global__ __launch_bounds__(256)
void gemm_up(const unsigned short* __restrict__ A, const unsigned short* __restrict__ Bt,
             const float* __restrict__ bias, unsigned short* __restrict__ Y2,
             float* __restrict__ partial)
{
    __shared__ short Asm[BM * BK];
    __shared__ short Bsm[BN * BK];
    __shared__ float colred[BN];
    int tid = threadIdx.x;
    int lane = tid & 63, wv = tid >> 6;
    int wm = wv >> 1, wn = wv & 1;
    int lr = lane & 15, lq = lane >> 4;
    long m0 = (long)blockIdx.y * BM;
    int n0 = blockIdx.x * BN;

    f32x4 acc[4][2];
#pragma unroll
    for (int mi = 0; mi < 4; ++mi)
#pragma unroll
        for (int ni = 0; ni < 2; ++ni) acc[mi][ni] = (f32x4){0.f, 0.f, 0.f, 0.f};

    for (int k0 = 0; k0 < Cn; k0 += BK) {
        GEMM_STAGE(A, Cn, Bt, Cn);
        __syncthreads();
        GEMM_COMPUTE;
        __syncthreads();
    }

    float ss[2] = {0.f, 0.f};
#pragma unroll
    for (int mi = 0; mi < 4; ++mi) {
#pragma unroll
        for (int ni = 0; ni < 2; ++ni) {
            int colg = n0 + wn * 32 + ni * 16 + lr;
            float bb = bias[colg];
            long mbase = m0 + wm * 64 + mi * 16 + lq * 4;
#pragma unroll
            for (int i = 0; i < 4; ++i) {
                float v = acc[mi][ni][i] + bb;
                v = 0.5f * v * (1.0f + erff(v * 0.70710678118654752f));
                ss[ni] = fmaf(v, v, ss[ni]);
                Y2[(mbase + i) * C4 + colg] = f2bf(v);
            }
        }
    }
#pragma unroll
    for (int ni = 0; ni < 2; ++ni) {
        ss[ni] += __shfl_xor(ss[ni], 16);
        ss[ni] += __shfl_xor(ss[ni], 32);
    }
    if (wm == 0 && lq == 0) {
        colred[wn * 32 + lr]      = ss[0];
        colred[wn * 32 + 16 + lr] = ss[1];
    }
    __syncthreads();
    if (wm == 1 && lq == 0) {
        colred[wn * 32 + lr]      += ss[0];
        colred[wn * 32 + 16 + lr] += ss[1];
    }
    __syncthreads();
    if (tid < BN) partial[(size_t)blockIdx.y * C4 + n0 + tid] = colred[tid];
}

// ---- GEMM down: y2 @ w2s^T + beff + x, NDHWC -> NCDHW f32 ----
__global__ __launch_bounds__(256)
void gemm_down(const unsigned short* __restrict__ A, const unsigned short* __restrict__ Bt,
               const float* __restrict__ beff, const float* __restrict__ x,
               float* __restrict__ out)
{
    __shared__ short Asm[BM * BK];
    __shared__ short Bsm[BN * BK];
    int tid = threadIdx.x;
    int lane = tid & 63, wv = tid >> 6;
    int wm = wv >> 1, wn = wv & 1;
    int lr = lane & 15, lq = lane >> 4;
    long m0 = (long)blockIdx.y * BM;
    int n0 = blockIdx.x * BN;

    f32x4 acc[4][2];
#pragma unroll
    for (int mi = 0; mi < 4; ++mi)
#pragma unroll
        for (int ni = 0; ni < 2; ++ni) acc[mi][ni] = (f32x4){0.f, 0.f, 0.f, 0.f};

    for (int k0 = 0; k0 < C4; k0 += BK) {
        GEMM_STAGE(A, C4, Bt, C4);
        __syncthreads();
        GEMM_COMPUTE;
        __syncthreads();
    }

#pragma unroll
    for (int mi = 0; mi < 4; ++mi) {
#pragma unroll
        for (int ni = 0; ni < 2; ++ni) {
            int colg = n0 + wn * 32 + ni * 16 + lr;
            float be = beff[colg];
            long mbase = m0 + wm * 64 + mi * 16 + lq * 4;
            const float* xp = x + (long)colg * DHW + mbase;
            float* op = out + (long)colg * DHW + mbase;
            float4 xvv = *(const float4*)xp;
            float4 o;
            o.x = acc[mi][ni][0] + be + xvv.x;
            o.y = acc[mi][ni][1] + be + xvv.y;
            o.z = acc[mi][ni][2] + be + xvv.z;
            o.w = acc[mi][ni][3] + be + xvv.w;
            *(float4*)op = o;
        }
    }
}

// ---------------- GRN reduce: 864 partials -> gx2[n] ----------------
__global__ __launch_bounds__(256)
void grn_reduce(const float* __restrict__ partial, float* __restrict__ gx2)
{
    int n = blockIdx.x;
    const float* p = partial + n;
    float s = 0.f;
    for (int r = threadIdx.x; r < 864; r += 256) s += p[(long)r * C4];
    __shared__ float red[256];
    red[threadIdx.x] = s; __syncthreads();
    for (int st = 128; st > 0; st >>= 1) {
        if (threadIdx.x < st) red[threadIdx.x] += red[threadIdx.x + st];
        __syncthreads();
    }
    if (threadIdx.x == 0) gx2[n] = red[0];
}

// ---------------- effective down-bias: beff[j] = b2[j] + sum_k beta[k] W2[k][j] ----
__global__ __launch_bounds__(256)
void bias_eff_k(const float* __restrict__ beta, const float* __restrict__ W2,
                const float* __restrict__ b2, float* __restrict__ beff)
{
    __shared__ float red[256];
    int j = blockIdx.x, t = threadIdx.x;
    float s = 0.f;
#pragma unroll
    for (int i = 0; i < 3; ++i) {
        int k = t + i * 256;
        s = fmaf(beta[k], W2[(long)k * Cn + j], s);
    }
    red[t] = s; __syncthreads();
    for (int st = 128; st > 0; st >>= 1) {
        if (t < st) red[t] += red[t + st];
        __syncthreads();
    }
    if (t == 0) beff[j] = red[0] + b2[j];
}

extern "C" void kernel_launch(void* const* d_in, const int* in_sizes, int n_in,
                              void* d_out, int out_size, void* d_ws, size_t ws_size,
                              hipStream_t stream) {
    const float* x      = (const float*)d_in[0];
    const float* conv_w = (const float*)d_in[1];
    const float* conv_b = (const float*)d_in[2];
    const float* ln_g   = (const float*)d_in[3];
    const float* ln_b   = (const float*)d_in[4];
    const float* w1     = (const float*)d_in[5];
    const float* b1     = (const float*)d_in[6];
    const float* gg     = (const float*)d_in[7];
    const float* gb     = (const float*)d_in[8];
    const float* w2     = (const float*)d_in[9];
    const float* b2     = (const float*)d_in[10];
    float* out = (float*)d_out;
    char* ws = (char*)d_ws;

    unsigned short* y2  = (unsigned short*)(ws);                  // [M][768] bf16, overlaps yc
    unsigned short* yc  = (unsigned short*)(ws);                  // [192][DHW] bf16 (dead before y2)
    unsigned short* y1  = (unsigned short*)(ws + 169869312L);     // [M][192] bf16
    // btoep: 192*49*512 bf16 = 9,633,792 B, placed in y1's tail — live only
    // during conv, recomputed per batch (ln overwrites it afterwards).
    unsigned short* btp = (unsigned short*)(ws + 202702848L);
    float*     partial  = (float*)(ws + 212336640L);              // [864][768] f32
    unsigned short* w1t = (unsigned short*)(ws + 214990848L);     // [768][192] bf16
    unsigned short* w2s = (unsigned short*)(ws + 215285760L);     // [192][768] bf16
    float*         gx2  = (float*)(ws + 215580672L);
    float*        beff  = (float*)(ws + 215586816L);

    bias_eff_k<<<Cn, 256, 0, stream>>>(gb, w2, b2, beff);
    wtrans<<<(Cn * C4 + 255) / 256, 256, 0, stream>>>(w1, w1t, Cn, C4);

    for (int b = 0; b < Bn; ++b) {
        const float* xb = x + (size_t)b * CDHW;
        float* outb = out + (size_t)b * CDHW;
        btoep_k<<<(Cn * 49 * 64) / 256, 256, 0, stream>>>(conv_w, btp);
        dim3 gc(54, Cn);                  // 6x3x3 tiles of 8x16x16
        conv_dw<<<gc, 128, 0, stream>>>(xb, btp, conv_b, yc);
        ln_kernel<<<Dn * Hn, 256, 0, stream>>>(yc, ln_g, ln_b, y1);
        dim3 gu(C4 / BN, DHW / BM);
        gemm_up<<<gu, 256, 0, stream>>>(y1, w1t, b1, y2, partial);
        grn_reduce<<<C4, 256, 0, stream>>>(partial, gx2);
        wscale<<<(Cn * C4) / 256, 256, 0, stream>>>(w2, gx2, gg, w2s);
        dim3 gd(Cn / BN, DHW / BM);
        gemm_down<<<gd, 256, 0, stream>>>(y2, w2s, beff, xb, outb);
    }
}

// Round 13
// 807.802 us; speedup vs baseline: 2.4843x; 1.1710x over previous
//
#include <hip/hip_runtime.h>
#include <math.h>

#define Bn 2
#define Cn 192
#define Dn 48
#define Hn 48
#define Wn 48
#define C4 768
#define DHW (Dn*Hn*Wn)          // 110592 per batch
#define CDHW ((long)Cn*DHW)     // 21233664 per batch

typedef __attribute__((ext_vector_type(8))) short bf16x8;
typedef __attribute__((ext_vector_type(4))) float f32x4;

__device__ inline float bf2f(unsigned short u) {
    union { float f; unsigned int i; } v; v.i = ((unsigned int)u) << 16; return v.f;
}
__device__ inline unsigned short f2bf(float f) {
    union { float f; unsigned int i; } v; v.f = f;
    unsigned int r = v.i + 0x7FFFu + ((v.i >> 16) & 1u);   // RNE
    return (unsigned short)(r >> 16);
}
__device__ inline float blo(unsigned int u) {
    union { unsigned int i; float f; } v; v.i = u << 16; return v.f;
}
__device__ inline float bhi(unsigned int u) {
    union { unsigned int i; float f; } v; v.i = u & 0xffff0000u; return v.f;
}
__device__ inline unsigned int cvtpk_bf16(float lo, float hi) {
    unsigned int r;
    asm("v_cvt_pk_bf16_f32 %0, %1, %2" : "=v"(r) : "v"(lo), "v"(hi));
    return r;
}

// ---- x pre-pad: NCDHW f32 -> xbf[c][d][h][64] bf16, w zero-padded +-8 ----
// Removes all per-element bounds checks / conversions from conv staging.
__global__ __launch_bounds__(256)
void xpad_k(const float* __restrict__ x, unsigned short* __restrict__ xbf)
{
    int u = blockIdx.x * 256 + threadIdx.x;     // row*8 + j
    int j = u & 7;
    int row = u >> 3;                            // c*2304 + d*48 + h
    unsigned short* orow = xbf + ((size_t)row << 6);
    uint4 o = {0u, 0u, 0u, 0u};
    if (j >= 1 && j <= 6) {
        const float* xr = x + (size_t)row * 48 + (8 * j - 8);
        float4 a = *(const float4*)xr;
        float4 b = *(const float4*)(xr + 4);
        o.x = cvtpk_bf16(a.x, a.y); o.y = cvtpk_bf16(a.z, a.w);
        o.z = cvtpk_bf16(b.x, b.y); o.w = cvtpk_bf16(b.z, b.w);
    }
    *(uint4*)(orow + 8 * j) = o;
}

// ---- B-Toeplitz table: btp[(c*49+kdkh)*64+lane][j] = wt[kdkh][8g+j-n-5] ----
// (n = lane&15, g = lane>>4; zero outside the band). Window starts at w0-8
// (padded layout), so the band shift is +5: out(n) needs k = n + kw + 5.
__global__ __launch_bounds__(256)
void btoep_k(const float* __restrict__ cw, unsigned short* __restrict__ btp)
{
    int idx = blockIdx.x * 256 + threadIdx.x;   // (c*49 + kdkh)*64 + lane
    int lane = idx & 63;
    int t = idx >> 6;
    int kdkh = t % 49, c = t / 49;
    int n = lane & 15, g = lane >> 4;
    unsigned short v[8];
#pragma unroll
    for (int j = 0; j < 8; ++j) {
        int kw = 8 * g + j - n - 5;
        v[j] = (kw >= 0 && kw <= 6) ? f2bf(cw[(kdkh * 7 + kw) * Cn + c])
                                    : (unsigned short)0;
    }
    *(uint4*)(btp + (size_t)idx * 8) = *(uint4*)v;
}

// ---------------- depthwise conv 7x7x7 on the MATRIX pipe (Toeplitz MFMA) ----
// block: 128 thr = 2 waves, one channel, 16d x 16h x 16w outputs; wave wv owns
// d-slices 8wv..8wv+7. Halo 22x22 rows x 32 bf16 (64B, chunk^=row&3 swizzle),
// staged from the padded xbf with ONE uint4 load + ds_write_b128 per quad.
// Per (kh, plane p): one ds_read_b128 A-frag feeds up to 7 MFMAs (acc[p-kd]).
#define CTD 16
#define CHD (CTD+6)   // 22
#define CHH 22

__global__ __launch_bounds__(128)
void conv_dw(const unsigned short* __restrict__ xbf, const unsigned short* __restrict__ btp,
             const float* __restrict__ cb, unsigned short* __restrict__ yc)
{
    __shared__ unsigned int xt[CHD * CHH * 16];   // 30,976 B
    int c = blockIdx.y;
    int s = blockIdx.x;                           // 27 tiles: 3x3x3 of 16^3
    int wt = s % 3, ht = (s / 3) % 3, dt = s / 9;
    int d0 = dt * 16, h0 = ht * 16, w0 = wt * 16;
    int tid = threadIdx.x;

    const unsigned short* xc = xbf + ((size_t)c * 2304 << 6);
    for (int u = tid; u < CHD * CHH * 4; u += 128) {
        int g = u & 3, r2 = u >> 2;
        int hh2 = r2 % CHH, dd = r2 / CHH;
        int gd = d0 - 3 + dd, gh = h0 - 3 + hh2;
        uint4 v = {0u, 0u, 0u, 0u};
        if ((unsigned)gd < 48u && (unsigned)gh < 48u)
            v = *(const uint4*)(xc + (((size_t)gd * 48 + gh) << 6) + w0 + 8 * g);
        *(uint4*)&xt[(r2 << 4) + ((g ^ (r2 & 3)) << 2)] = v;
    }
    __syncthreads();

    int lane = tid & 63, wv = tid >> 6;
    int lr = lane & 15, g = lane >> 4;
    float bias = cb[c];
    f32x4 acc[8];
#pragma unroll
    for (int t = 0; t < 8; ++t) acc[t] = (f32x4){bias, bias, bias, bias};

    const unsigned short* bchan = btp + (size_t)c * 49 * 512;
    const unsigned short* xt16 = (const unsigned short*)xt;

    for (int kh = 0; kh < 7; ++kh) {
        bf16x8 Bf[7];
#pragma unroll
        for (int kd = 0; kd < 7; ++kd)
            Bf[kd] = *(const bf16x8*)(bchan + (size_t)((kd * 7 + kh) * 64 + lane) * 8);
#pragma unroll
        for (int p = 0; p < 14; ++p) {
            int r2 = (8 * wv + p) * CHH + kh + lr;
            bf16x8 Af = *(const bf16x8*)(xt16 + (r2 << 5) + ((g ^ (r2 & 3)) << 3));
#pragma unroll
            for (int kd = 0; kd < 7; ++kd) {
                int t = p - kd;
                if (t < 0 || t > 7) continue;     // folds at compile time
                acc[t] = __builtin_amdgcn_mfma_f32_16x16x32_bf16(Af, Bf[kd], acc[t], 0, 0, 0);
            }
        }
    }

    unsigned short* yb = yc + (long)c * DHW;
#pragma unroll
    for (int t = 0; t < 8; ++t) {
        int d = d0 + 8 * wv + t;
#pragma unroll
        for (int i = 0; i < 4; ++i) {
            int h = h0 + g * 4 + i;
            yb[((long)d * 48 + h) * 48 + w0 + lr] = f2bf(acc[t][i]);
        }
    }
}

// ---------------- LayerNorm over C, per-batch NCDHW(bf16) -> NDHWC (bf16) ----------------
__global__ __launch_bounds__(256)
void ln_kernel(const unsigned short* __restrict__ yc, const float* __restrict__ g,
               const float* __restrict__ lb, unsigned short* __restrict__ y1)
{
    __shared__ float tile[Cn * Wn];
    __shared__ float qs1[4][48], qs2[4][48];
    __shared__ float mu_s[Wn], rs_s[Wn];
    int dh = blockIdx.x;
    long rowbase = (long)dh * Wn;
    for (int l = threadIdx.x; l < Cn * 24; l += 256) {
        int c = l / 24, wp = l % 24;
        unsigned int u = *(const unsigned int*)&yc[rowbase + (long)c * DHW + wp * 2];
        tile[c * Wn + wp * 2]     = blo(u);
        tile[c * Wn + wp * 2 + 1] = bhi(u);
    }
    __syncthreads();
    if (threadIdx.x < 192) {
        int w = threadIdx.x >> 2, q = threadIdx.x & 3;
        float s1 = 0.f, s2 = 0.f;
        for (int cc = 0; cc < 48; ++cc) {
            float v = tile[(cc * 4 + q) * Wn + w];
            s1 += v; s2 = fmaf(v, v, s2);
        }
        qs1[q][w] = s1; qs2[q][w] = s2;
    }
    __syncthreads();
    if (threadIdx.x < 48) {
        int w = threadIdx.x;
        float s1 = qs1[0][w] + qs1[1][w] + qs1[2][w] + qs1[3][w];
        float s2 = qs2[0][w] + qs2[1][w] + qs2[2][w] + qs2[3][w];
        float mu = s1 * (1.0f / Cn);
        float var = s2 * (1.0f / Cn) - mu * mu;
        mu_s[w] = mu;
        rs_s[w] = rsqrtf(var + 1e-6f);
    }
    __syncthreads();
    long obase = (long)dh * Wn * Cn;
    for (int l = threadIdx.x; l < Cn * Wn; l += 256) {
        int w = l / Cn, c = l % Cn;
        float val = (tile[c * Wn + w] - mu_s[w]) * rs_s[w] * g[c] + lb[c];
        y1[obase + l] = f2bf(val);
    }
}

// ---------------- weight transpose+bf16: Wt[n][k] = bf16(W[k][n]) ----------------
__global__ __launch_bounds__(256)
void wtrans(const float* __restrict__ W, unsigned short* __restrict__ Wt, int K, int N)
{
    int idx = blockIdx.x * 256 + threadIdx.x;
    if (idx >= K * N) return;
    int n = idx / K, k = idx % K;
    Wt[idx] = f2bf(W[(long)k * N + n]);
}

// ---- W2 scale+transpose with fused GRN snx: W2s[n][k] = bf16(W2[k][n]*snx[k]) ----
__global__ __launch_bounds__(256)
void wscale(const float* __restrict__ W2, const float* __restrict__ gx2,
            const float* __restrict__ gamma, unsigned short* __restrict__ W2s)
{
    __shared__ float red[256];
    int t = threadIdx.x;
    float s = 0.f;
#pragma unroll
    for (int i = 0; i < 3; ++i) s += sqrtf(gx2[t + i * 256]);
    red[t] = s; __syncthreads();
    for (int st = 128; st > 0; st >>= 1) {
        if (t < st) red[t] += red[t + st];
        __syncthreads();
    }
    float inv = 1.0f / (red[0] * (1.0f / C4) + 1e-6f);
    int idx = blockIdx.x * 256 + t;          // [n][k], k fastest
    int n = idx / C4, k = idx % C4;
    float snx = 1.0f + gamma[k] * sqrtf(gx2[k]) * inv;
    W2s[idx] = f2bf(W2[(long)k * Cn + n] * snx);
}

// ================= MFMA GEMM: C[M,N] = A[M,K](bf16) @ Bt[N,K](bf16)^T =========
#define BM 128
#define BN 64
#define BK 64

#define GEMM_STAGE(Aptr, Astride, Btptr, Bstride)                               \
    {                                                                           \
        _Pragma("unroll")                                                       \
        for (int i = 0; i < 4; ++i) {                                           \
            int chunk = i * 256 + tid;                                          \
            int r = chunk >> 3, cc = chunk & 7;                                 \
            bf16x8 v = *(const bf16x8*)((Aptr) + (size_t)(m0 + r) * (Astride) + k0 + cc * 8); \
            *(bf16x8*)&Asm[r * BK + ((cc ^ (r & 7)) * 8)] = v;                  \
        }                                                                       \
        _Pragma("unroll")                                                       \
        for (int i = 0; i < 2; ++i) {                                           \
            int chunk = i * 256 + tid;                                          \
            int r = chunk >> 3, cc = chunk & 7;                                 \
            bf16x8 v = *(const bf16x8*)((Btptr) + (size_t)(n0 + r) * (Bstride) + k0 + cc * 8); \
            *(bf16x8*)&Bsm[r * BK + ((cc ^ (r & 7)) * 8)] = v;                  \
        }                                                                       \
    }

#define GEMM_COMPUTE                                                            \
    _Pragma("unroll")                                                           \
    for (int kk = 0; kk < 2; ++kk) {                                            \
        bf16x8 af[4], bfr[2];                                                   \
        _Pragma("unroll")                                                       \
        for (int mi = 0; mi < 4; ++mi) {                                        \
            int r = wm * 64 + mi * 16 + lr;                                     \
            int cc = (kk * 4 + lq) ^ (r & 7);                                   \
            af[mi] = *(const bf16x8*)&Asm[r * BK + cc * 8];                     \
        }                                                                       \
        _Pragma("unroll")                                                       \
        for (int ni = 0; ni < 2; ++ni) {                                        \
            int r = wn * 32 + ni * 16 + lr;                                     \
            int cc = (kk * 4 + lq) ^ (r & 7);                                   \
            bfr[ni] = *(const bf16x8*)&Bsm[r * BK + cc * 8];                    \
        }                                                                       \
        _Pragma("unroll")                                                       \
        for (int mi = 0; mi < 4; ++mi)                                          \
            _Pragma("unroll")                                                   \
            for (int ni = 0; ni < 2; ++ni)                                      \
                acc[mi][ni] = __builtin_amdgcn_mfma_f32_16x16x32_bf16(          \
                    af[mi], bfr[ni], acc[mi][ni], 0, 0, 0);                     \
    }

// ---- GEMM up: y1 @ w1t^T + b1, GELU -> y2 bf16; fused GRN column partials ----
__global__ __launch_bounds__(256)
void gemm_up(const unsigned short* __restrict__ A, const unsigned short* __restrict__ Bt,
             const float* __restrict__ bias, unsigned short* __restrict__ Y2,
             float* __restrict__ partial)
{
    __shared__ short Asm[BM * BK];
    __shared__ short Bsm[BN * BK];
    __shared__ float colred[BN];
    int tid = threadIdx.x;
    int lane = tid & 63, wv = tid >> 6;
    int wm = wv >> 1, wn = wv & 1;
    int lr = lane & 15, lq = lane >> 4;
    long m0 = (long)blockIdx.y * BM;
    int n0 = blockIdx.x * BN;

    f32x4 acc[4][2];
#pragma unroll
    for (int mi = 0; mi < 4; ++mi)
#pragma unroll
        for (int ni = 0; ni < 2; ++ni) acc[mi][ni] = (f32x4){0.f, 0.f, 0.f, 0.f};

    for (int k0 = 0; k0 < Cn; k0 += BK) {
        GEMM_STAGE(A, Cn, Bt, Cn);
        __syncthreads();
        GEMM_COMPUTE;
        __syncthreads();
    }

    float ss[2] = {0.f, 0.f};
#pragma unroll
    for (int mi = 0; mi < 4; ++mi) {
#pragma unroll
        for (int ni = 0; ni < 2; ++ni) {
            int colg = n0 + wn * 32 + ni * 16 + lr;
            float bb = bias[colg];
            long mbase = m0 + wm * 64 + mi * 16 + lq * 4;
#pragma unroll
            for (int i = 0; i < 4; ++i) {
                float v = acc[mi][ni][i] + bb;
                v = 0.5f * v * (1.0f + erff(v * 0.70710678118654752f));
                ss[ni] = fmaf(v, v, ss[ni]);
                Y2[(mbase + i) * C4 + colg] = f2bf(v);
            }
        }
    }
#pragma unroll
    for (int ni = 0; ni < 2; ++ni) {
        ss[ni] += __shfl_xor(ss[ni], 16);
        ss[ni] += __shfl_xor(ss[ni], 32);
    }
    if (wm == 0 && lq == 0) {
        colred[wn * 32 + lr]      = ss[0];
        colred[wn * 32 + 16 + lr] = ss[1];
    }
    __syncthreads();
    if (wm == 1 && lq == 0) {
        colred[wn * 32 + lr]      += ss[0];
        colred[wn * 32 + 16 + lr] += ss[1];
    }
    __syncthreads();
    if (tid < BN) partial[(size_t)blockIdx.y * C4 + n0 + tid] = colred[tid];
}

// ---- GEMM down: y2 @ w2s^T + beff + x, NDHWC -> NCDHW f32 ----
__global__ __launch_bounds__(256)
void gemm_down(const unsigned short* __restrict__ A, const unsigned short* __restrict__ Bt,
               const float* __restrict__ beff, const float* __restrict__ x,
               float* __restrict__ out)
{
    __shared__ short Asm[BM * BK];
    __shared__ short Bsm[BN * BK];
    int tid = threadIdx.x;
    int lane = tid & 63, wv = tid >> 6;
    int wm = wv >> 1, wn = wv & 1;
    int lr = lane & 15, lq = lane >> 4;
    long m0 = (long)blockIdx.y * BM;
    int n0 = blockIdx.x * BN;

    f32x4 acc[4][2];
#pragma unroll
    for (int mi = 0; mi < 4; ++mi)
#pragma unroll
        for (int ni = 0; ni < 2; ++ni) acc[mi][ni] = (f32x4){0.f, 0.f, 0.f, 0.f};

    for (int k0 = 0; k0 < C4; k0 += BK) {
        GEMM_STAGE(A, C4, Bt, C4);
        __syncthreads();
        GEMM_COMPUTE;
        __syncthreads();
    }

#pragma unroll
    for (int mi = 0; mi < 4; ++mi) {
#pragma unroll
        for (int ni = 0; ni < 2; ++ni) {
            int colg = n0 + wn * 32 + ni * 16 + lr;
            float be = beff[colg];
            long mbase = m0 + wm * 64 + mi * 16 + lq * 4;
            const float* xp = x + (long)colg * DHW + mbase;
            float* op = out + (long)colg * DHW + mbase;
            float4 xvv = *(const float4*)xp;
            float4 o;
            o.x = acc[mi][ni][0] + be + xvv.x;
            o.y = acc[mi][ni][1] + be + xvv.y;
            o.z = acc[mi][ni][2] + be + xvv.z;
            o.w = acc[mi][ni][3] + be + xvv.w;
            *(float4*)op = o;
        }
    }
}

// ---------------- GRN reduce: 864 partials -> gx2[n] ----------------
__global__ __launch_bounds__(256)
void grn_reduce(const float* __restrict__ partial, float* __restrict__ gx2)
{
    int n = blockIdx.x;
    const float* p = partial + n;
    float s = 0.f;
    for (int r = threadIdx.x; r < 864; r += 256) s += p[(long)r * C4];
    __shared__ float red[256];
    red[threadIdx.x] = s; __syncthreads();
    for (int st = 128; st > 0; st >>= 1) {
        if (threadIdx.x < st) red[threadIdx.x] += red[threadIdx.x + st];
        __syncthreads();
    }
    if (threadIdx.x == 0) gx2[n] = red[0];
}

// ---------------- effective down-bias: beff[j] = b2[j] + sum_k beta[k] W2[k][j] ----
__global__ __launch_bounds__(256)
void bias_eff_k(const float* __restrict__ beta, const float* __restrict__ W2,
                const float* __restrict__ b2, float* __restrict__ beff)
{
    __shared__ float red[256];
    int j = blockIdx.x, t = threadIdx.x;
    float s = 0.f;
#pragma unroll
    for (int i = 0; i < 3; ++i) {
        int k = t + i * 256;
        s = fmaf(beta[k], W2[(long)k * Cn + j], s);
    }
    red[t] = s; __syncthreads();
    for (int st = 128; st > 0; st >>= 1) {
        if (t < st) red[t] += red[t + st];
        __syncthreads();
    }
    if (t == 0) beff[j] = red[0] + b2[j];
}

extern "C" void kernel_launch(void* const* d_in, const int* in_sizes, int n_in,
                              void* d_out, int out_size, void* d_ws, size_t ws_size,
                              hipStream_t stream) {
    const float* x      = (const float*)d_in[0];
    const float* conv_w = (const float*)d_in[1];
    const float* conv_b = (const float*)d_in[2];
    const float* ln_g   = (const float*)d_in[3];
    const float* ln_b   = (const float*)d_in[4];
    const float* w1     = (const float*)d_in[5];
    const float* b1     = (const float*)d_in[6];
    const float* gg     = (const float*)d_in[7];
    const float* gb     = (const float*)d_in[8];
    const float* w2     = (const float*)d_in[9];
    const float* b2     = (const float*)d_in[10];
    float* out = (float*)d_out;
    char* ws = (char*)d_ws;

    // liveness-overlapped layout (~216 MB):
    //   [0, 42.5M)      yc   bf16 [192][DHW]           (conv out; dead after ln)
    //   [42.5M, 99.1M)  xbf  bf16 [192][48][48][64]    (padded x; dead after conv)
    //   [0, 169.9M)     y2   bf16 [M][768]             (gemm_up out; overlaps both)
    //   [169.9M,212.3M) y1   bf16 [M][192]; btp in its tail (live conv-only)
    unsigned short* yc  = (unsigned short*)(ws);
    unsigned short* xbf = (unsigned short*)(ws + 42467328L);
    unsigned short* y2  = (unsigned short*)(ws);
    unsigned short* y1  = (unsigned short*)(ws + 169869312L);
    unsigned short* btp = (unsigned short*)(ws + 202702848L);
    float*     partial  = (float*)(ws + 212336640L);
    unsigned short* w1t = (unsigned short*)(ws + 214990848L);
    unsigned short* w2s = (unsigned short*)(ws + 215285760L);
    float*         gx2  = (float*)(ws + 215580672L);
    float*        beff  = (float*)(ws + 215586816L);

    bias_eff_k<<<Cn, 256, 0, stream>>>(gb, w2, b2, beff);
    wtrans<<<(Cn * C4 + 255) / 256, 256, 0, stream>>>(w1, w1t, Cn, C4);

    for (int b = 0; b < Bn; ++b) {
        const float* xb = x + (size_t)b * CDHW;
        float* outb = out + (size_t)b * CDHW;
        xpad_k<<<(Cn * 2304 * 8) / 256, 256, 0, stream>>>(xb, xbf);
        btoep_k<<<(Cn * 49 * 64) / 256, 256, 0, stream>>>(conv_w, btp);
        dim3 gc(27, Cn);                  // 3x3x3 tiles of 16^3
        conv_dw<<<gc, 128, 0, stream>>>(xbf, btp, conv_b, yc);
        ln_kernel<<<Dn * Hn, 256, 0, stream>>>(yc, ln_g, ln_b, y1);
        dim3 gu(C4 / BN, DHW / BM);
        gemm_up<<<gu, 256, 0, stream>>>(y1, w1t, b1, y2, partial);
        grn_reduce<<<C4, 256, 0, stream>>>(partial, gx2);
        wscale<<<(Cn * C4) / 256, 256, 0, stream>>>(w2, gx2, gg, w2s);
        dim3 gd(Cn / BN, DHW / BM);
        gemm_down<<<gd, 256, 0, stream>>>(y2, w2s, beff, xb, outb);
    }
}